// Round 8
// baseline (2883.753 us; speedup 1.0000x reference)
//
#include <hip/hip_runtime.h>
#include <cstdint>
#include <cstddef>

// ---------------------------------------------------------------------------
// LSTM T=512 B=64 I=256 H=512  (fp32 in/out, bf16 MFMA compute)
//
// Phase A (prep):    pack Wall/Uall bf16, ball=bW+bU (f32), zero sync flags.
// Phase B (xw_gemm): xw[t*64+b][4H] = x @ Wall^T + ball, bf16 out.
// Phase C (scan):    64 persistent WGs = 4 batch-groups x 16 hidden-slices.
//                    U slice in VGPRs for all 512 steps. R0-proven handoff
//                    protocol (events byte-identical): h via relaxed agent
//                    atomics (L3), per-group 16-flag line, spin w/ s_sleep(1),
//                    barrier-drained tid0 publish.
//                    R8 delta (consumer ladder only):
//                    (a) per-WAVE spin: lanes 0..15 of every wave poll the 16
//                        flags (same condition as R0's spin) -> post-spin WG
//                        barrier deleted;
//                    (b) h loaded DIRECTLY into MFMA A-fragments via 8B agent
//                        atomic loads (fragment = 8 contiguous bf16 of one
//                        h row) -> hstage LDS write+barrier+read deleted.
//                    Barriers/step: 4 -> 2. WAR safety: every wave checks all
//                    16 flags; publish(t+1) is behind drain barrier <- gates
//                    barrier <- all fragment loads, so peers' slot overwrites
//                    (gated on our flag) still follow all our reads.
// ---------------------------------------------------------------------------

typedef __attribute__((ext_vector_type(8))) short short8;
typedef __attribute__((ext_vector_type(4))) float float4v;

typedef union { unsigned long long u[2]; short8 s8; } frag_t;

__device__ __forceinline__ unsigned short f2bf(float f) {
  unsigned u = __float_as_uint(f);
  u = u + 0x7FFFu + ((u >> 16) & 1u);   // RNE
  return (unsigned short)(u >> 16);
}
__device__ __forceinline__ float bf2f(unsigned short s) {
  return __uint_as_float(((unsigned)s) << 16);
}
__device__ __forceinline__ unsigned long long pack4(float4 v) {
  return (unsigned long long)f2bf(v.x) |
         ((unsigned long long)f2bf(v.y) << 16) |
         ((unsigned long long)f2bf(v.z) << 32) |
         ((unsigned long long)f2bf(v.w) << 48);
}

// ------------------------------ Phase A ------------------------------------
__global__ void prep_kernel(
    const float* __restrict__ Wf, const float* __restrict__ bWf,
    const float* __restrict__ Wi, const float* __restrict__ bWi,
    const float* __restrict__ Wo, const float* __restrict__ bWo,
    const float* __restrict__ Wc, const float* __restrict__ bWc,
    const float* __restrict__ Uf, const float* __restrict__ bUf,
    const float* __restrict__ Ui, const float* __restrict__ bUi,
    const float* __restrict__ Uo, const float* __restrict__ bUo,
    const float* __restrict__ Uc, const float* __restrict__ bUc,
    unsigned short* __restrict__ Wall, unsigned short* __restrict__ Uall,
    float* __restrict__ ball, int* __restrict__ flags)
{
  const float* Ws[4]  = {Wf, Wi, Wo, Wc};
  const float* Us[4]  = {Uf, Ui, Uo, Uc};
  const float* bWs[4] = {bWf, bWi, bWo, bWc};
  const float* bUs[4] = {bUf, bUi, bUo, bUc};
  const long long NW4 = 131072;   // 2048*256/4
  const long long NU4 = 262144;   // 2048*512/4
  const long long NB4 = 512;      // 2048/4
  const long long TOT = NW4 + NU4 + NB4;
  long long idx0 = (long long)blockIdx.x * blockDim.x + threadIdx.x;
  if (idx0 < 64) flags[idx0] = 0;
  long long stride = (long long)gridDim.x * blockDim.x;
  for (long long u = idx0; u < TOT; u += stride) {
    if (u < NW4) {
      int e = (int)(u << 2);
      int n = e >> 8, k = e & 255;
      float4 v = *(const float4*)(Ws[n >> 9] + (size_t)(n & 511) * 256 + k);
      ((unsigned long long*)Wall)[u] = pack4(v);
    } else if (u < NW4 + NU4) {
      long long q = u - NW4;
      int e = (int)(q << 2);
      int n = e >> 9, k = e & 511;
      float4 v = *(const float4*)(Us[n >> 9] + (size_t)(n & 511) * 512 + k);
      ((unsigned long long*)Uall)[q] = pack4(v);
    } else {
      long long q = u - NW4 - NU4;
      int e = (int)(q << 2);
      int gate = e >> 9, r = e & 511;
      float4 a = *(const float4*)(bWs[gate] + r);
      float4 b = *(const float4*)(bUs[gate] + r);
      float4 sv;
      sv.x = a.x + b.x; sv.y = a.y + b.y; sv.z = a.z + b.z; sv.w = a.w + b.w;
      *(float4*)(ball + e) = sv;
    }
  }
}

// ------------------------------ Phase B ------------------------------------
// xw[m][n] = sum_k x[m][k]*Wall[n][k] + ball[n],  M=32768 N=2048 K=256.
// 128x128 tile, BK=64, 4 waves in 2x2, each wave 64x64 (16 accs).
__global__ __launch_bounds__(256, 2) void xw_gemm(
    const float* __restrict__ x,
    const unsigned short* __restrict__ Wall,
    const float* __restrict__ ball,
    unsigned short* __restrict__ xw)
{
  __shared__ short As[128 * 72];
  __shared__ short Bs[128 * 72];
  const int tid = threadIdx.x;
  const int bn = blockIdx.x, bm = blockIdx.y;
  const int Mbase = bm * 128, Nbase = bn * 128;
  const int w = tid >> 6, L = tid & 63, lq = L >> 4, lr = L & 15;
  const int wm = w >> 1, wn = w & 1;
  const int srow = tid >> 1, shalf = tid & 1;  // staging: 32 elems per thread

  float4v acc[4][4];
  #pragma unroll
  for (int a = 0; a < 4; ++a)
    #pragma unroll
    for (int b = 0; b < 4; ++b) acc[a][b] = (float4v){0.f, 0.f, 0.f, 0.f};

  for (int ko = 0; ko < 256; ko += 64) {
    const float* gaf = x + (size_t)(Mbase + srow) * 256 + ko + shalf * 32;
    float4 f0 = *(const float4*)(gaf);
    float4 f1 = *(const float4*)(gaf + 4);
    float4 f2 = *(const float4*)(gaf + 8);
    float4 f3 = *(const float4*)(gaf + 12);
    float4 f4 = *(const float4*)(gaf + 16);
    float4 f5 = *(const float4*)(gaf + 20);
    float4 f6 = *(const float4*)(gaf + 24);
    float4 f7 = *(const float4*)(gaf + 28);
    const unsigned short* gb = Wall + (size_t)(Nbase + srow) * 256 + ko + shalf * 32;
    short8 b0 = *(const short8*)(gb);
    short8 b1 = *(const short8*)(gb + 8);
    short8 b2 = *(const short8*)(gb + 16);
    short8 b3 = *(const short8*)(gb + 24);
    __syncthreads();  // protect previous iteration's LDS reads
    {
      unsigned long long* pa = (unsigned long long*)&As[srow * 72 + shalf * 32];
      pa[0] = pack4(f0); pa[1] = pack4(f1);
      pa[2] = pack4(f2); pa[3] = pack4(f3);
      pa[4] = pack4(f4); pa[5] = pack4(f5);
      pa[6] = pack4(f6); pa[7] = pack4(f7);
      short* pb = &Bs[srow * 72 + shalf * 32];
      *(short8*)(pb) = b0; *(short8*)(pb + 8) = b1;
      *(short8*)(pb + 16) = b2; *(short8*)(pb + 24) = b3;
    }
    __syncthreads();
    #pragma unroll
    for (int kk = 0; kk < 64; kk += 32) {
      short8 af[4], bfr[4];
      #pragma unroll
      for (int mi = 0; mi < 4; ++mi)
        af[mi] = *(const short8*)&As[(wm * 64 + mi * 16 + lr) * 72 + kk + lq * 8];
      #pragma unroll
      for (int ni = 0; ni < 4; ++ni)
        bfr[ni] = *(const short8*)&Bs[(wn * 64 + ni * 16 + lr) * 72 + kk + lq * 8];
      #pragma unroll
      for (int mi = 0; mi < 4; ++mi)
        #pragma unroll
        for (int ni = 0; ni < 4; ++ni)
          acc[mi][ni] = __builtin_amdgcn_mfma_f32_16x16x32_bf16(
              af[mi], bfr[ni], acc[mi][ni], 0, 0, 0);
    }
  }
  // epilogue: +bias, bf16 store
  #pragma unroll
  for (int ni = 0; ni < 4; ++ni) {
    int col = Nbase + wn * 64 + ni * 16 + lr;
    float bias = ball[col];
    #pragma unroll
    for (int mi = 0; mi < 4; ++mi) {
      #pragma unroll
      for (int r = 0; r < 4; ++r) {
        int row = Mbase + wm * 64 + mi * 16 + lq * 4 + r;
        xw[(size_t)row * 2048 + col] = f2bf(acc[mi][ni][r] + bias);
      }
    }
  }
}

// ------------------------------ Phase C ------------------------------------
// 64 WGs: g = wg>>4 (batch group, 16 rows), s = wg&15 (hidden slice, 32 cols).
// Wave w (0..3) = gate w (f,i,o,c): U rows w*512+s*32..+32 held in VGPRs.
// h handoff: relaxed agent atomics (L3-coherent); R0 protocol, R8 consumer.
__global__ __launch_bounds__(256, 1) void lstm_scan(
    const unsigned short* __restrict__ xw,
    const unsigned short* __restrict__ Uall,
    unsigned short* __restrict__ hbuf,   // [2][64][512] bf16
    int* __restrict__ flags,             // [4][16]
    float* __restrict__ out)
{
  __shared__ float gates[4 * 16 * 33];        // mfma gate outputs (f32)
  __shared__ unsigned short xwb[4 * 16 * 32]; // xw tile (bf16)

  const int tid = threadIdx.x;
  const int wg = blockIdx.x;
  const int g = wg >> 4;
  const int s = wg & 15;
  const int w = tid >> 6, L = tid & 63, lq = L >> 4, lr = L & 15;

  // elementwise ownership: (batch row eb, col pair ej, ej+1)
  const int eb = tid >> 4;
  const int ej = (tid & 15) * 2;
  // xw prefetch mapping: thread -> (batch xb, gate xg, 8-col chunk xc)
  const int xb = tid >> 4, xg = (tid >> 2) & 3, xc = tid & 3;

  float* hseq = out;                                // T*B*H
  float* hfin = out + (size_t)512 * 64 * 512;
  float* cfin = hfin + (size_t)64 * 512;
  int* grp_flags = flags + g * 16;

  // --- U fragments into registers (held across the whole t-loop) ---
  short8 uf[2][16];
  #pragma unroll
  for (int nt = 0; nt < 2; ++nt)
    #pragma unroll
    for (int kt = 0; kt < 16; ++kt) {
      const unsigned short* p = Uall +
          (size_t)(w * 512 + s * 32 + nt * 16 + lr) * 512 + kt * 32 + lq * 8;
      uf[nt][kt] = *(const short8*)p;
    }

  float c0 = 0.f, c1 = 0.f, h0 = 0.f, h1 = 0.f;

  for (int t = 0; t < 512; ++t) {
    // prefetch xw for this step (overlaps the flag spin)
    const unsigned short* xp = xw +
        ((size_t)(t * 64 + g * 16 + xb)) * 2048 + xg * 512 + s * 32 + xc * 8;
    short8 xv = *(const short8*)xp;

    float4v a0a = (float4v){0.f, 0.f, 0.f, 0.f};
    float4v a0b = (float4v){0.f, 0.f, 0.f, 0.f};
    float4v a1a = (float4v){0.f, 0.f, 0.f, 0.f};
    float4v a1b = (float4v){0.f, 0.f, 0.f, 0.f};

    if (t > 0) {
      // per-WAVE spin: lanes 0..15 of EVERY wave poll the 16 flags; the wave
      // exits when all 16 >= t (same condition as R0's spin, no WG barrier).
      if (L < 16) {
        while (__hip_atomic_load(&grp_flags[L], __ATOMIC_RELAXED,
                                 __HIP_MEMORY_SCOPE_AGENT) < t)
          __builtin_amdgcn_s_sleep(1);
      }
      // fragment-direct h loads: 8 contiguous bf16 of row lr per fragment.
      const unsigned long long* hrow = (const unsigned long long*)
          (hbuf + ((size_t)((t - 1) & 1)) * 32768 +
           ((size_t)(g * 16 + lr)) * 512);
      frag_t fa[8], fb[8];
      #pragma unroll
      for (int kt = 0; kt < 8; ++kt) {
        fa[kt].u[0] = __hip_atomic_load(hrow + kt * 8 + lq * 2,
                                        __ATOMIC_RELAXED,
                                        __HIP_MEMORY_SCOPE_AGENT);
        fa[kt].u[1] = __hip_atomic_load(hrow + kt * 8 + lq * 2 + 1,
                                        __ATOMIC_RELAXED,
                                        __HIP_MEMORY_SCOPE_AGENT);
        fb[kt].u[0] = __hip_atomic_load(hrow + 64 + kt * 8 + lq * 2,
                                        __ATOMIC_RELAXED,
                                        __HIP_MEMORY_SCOPE_AGENT);
        fb[kt].u[1] = __hip_atomic_load(hrow + 64 + kt * 8 + lq * 2 + 1,
                                        __ATOMIC_RELAXED,
                                        __HIP_MEMORY_SCOPE_AGENT);
      }
      // 4 parallel dependency chains of 8 MFMAs each
      #pragma unroll
      for (int kt = 0; kt < 8; ++kt) {
        a0a = __builtin_amdgcn_mfma_f32_16x16x32_bf16(fa[kt].s8, uf[0][kt], a0a, 0, 0, 0);
        a0b = __builtin_amdgcn_mfma_f32_16x16x32_bf16(fb[kt].s8, uf[0][kt + 8], a0b, 0, 0, 0);
        a1a = __builtin_amdgcn_mfma_f32_16x16x32_bf16(fa[kt].s8, uf[1][kt], a1a, 0, 0, 0);
        a1b = __builtin_amdgcn_mfma_f32_16x16x32_bf16(fb[kt].s8, uf[1][kt + 8], a1b, 0, 0, 0);
      }
    }
    float4v acc0 = a0a + a0b;
    float4v acc1 = a1a + a1b;

    // gate tile -> LDS (f32), xw tile -> LDS (bf16)
    #pragma unroll
    for (int r = 0; r < 4; ++r) {
      gates[w * 528 + (lq * 4 + r) * 33 + lr] = acc0[r];
      gates[w * 528 + (lq * 4 + r) * 33 + 16 + lr] = acc1[r];
    }
    *(short8*)&xwb[xg * 512 + xb * 32 + xc * 8] = xv;
    __syncthreads();

    // elementwise LSTM cell for (eb, ej) and (eb, ej+1)
    {
      float gf = gates[eb * 33 + ej] + bf2f(xwb[eb * 32 + ej]);
      float gi = gates[528 + eb * 33 + ej] + bf2f(xwb[512 + eb * 32 + ej]);
      float go = gates[1056 + eb * 33 + ej] + bf2f(xwb[1024 + eb * 32 + ej]);
      float gc = gates[1584 + eb * 33 + ej] + bf2f(xwb[1536 + eb * 32 + ej]);
      float f_ = 1.f / (1.f + __expf(-gf));
      float i_ = 1.f / (1.f + __expf(-gi));
      float o_ = 1.f / (1.f + __expf(-go));
      float ct = 1.f - 2.f / (__expf(2.f * gc) + 1.f);
      c0 = f_ * c0 + i_ * ct;
      h0 = o_ * (1.f - 2.f / (__expf(2.f * c0) + 1.f));
    }
    {
      int j = ej + 1;
      float gf = gates[eb * 33 + j] + bf2f(xwb[eb * 32 + j]);
      float gi = gates[528 + eb * 33 + j] + bf2f(xwb[512 + eb * 32 + j]);
      float go = gates[1056 + eb * 33 + j] + bf2f(xwb[1024 + eb * 32 + j]);
      float gc = gates[1584 + eb * 33 + j] + bf2f(xwb[1536 + eb * 32 + j]);
      float f_ = 1.f / (1.f + __expf(-gf));
      float i_ = 1.f / (1.f + __expf(-gi));
      float o_ = 1.f / (1.f + __expf(-go));
      float ct = 1.f - 2.f / (__expf(2.f * gc) + 1.f);
      c1 = f_ * c1 + i_ * ct;
      h1 = o_ * (1.f - 2.f / (__expf(2.f * c1) + 1.f));
    }
    // h handoff (coherent 4B atomic store to L3)
    unsigned hb = ((unsigned)f2bf(h1) << 16) | (unsigned)f2bf(h0);
    unsigned* hdst = (unsigned*)(hbuf + ((size_t)(t & 1)) * 32768 +
                                 ((size_t)(g * 16 + eb)) * 512 + s * 32 + ej);
    __hip_atomic_store(hdst, hb, __ATOMIC_RELAXED, __HIP_MEMORY_SCOPE_AGENT);

    __syncthreads();  // vmcnt(0) drain: all h stores at L3 before flag
    if (tid == 0)
      __hip_atomic_store(&grp_flags[s], t + 1, __ATOMIC_RELAXED,
                         __HIP_MEMORY_SCOPE_AGENT);

    // hseq out AFTER publish (never read in-kernel; retire overlaps spin)
    size_t orow = ((size_t)(t * 64 + g * 16 + eb)) * 512 + s * 32 + ej;
    {
      float2 hv2 = make_float2(h0, h1);
      __builtin_nontemporal_store(*(double*)&hv2, (double*)(hseq + orow));
    }
  }

  // final states
  size_t fo = ((size_t)(g * 16 + eb)) * 512 + s * 32 + ej;
  *(float2*)(hfin + fo) = make_float2(h0, h1);
  *(float2*)(cfin + fo) = make_float2(c0, c1);
}

// ------------------------------ launch -------------------------------------
extern "C" void kernel_launch(void* const* d_in, const int* in_sizes, int n_in,
                              void* d_out, int out_size, void* d_ws, size_t ws_size,
                              hipStream_t stream) {
  (void)in_sizes; (void)n_in; (void)out_size; (void)ws_size;
  const float* x   = (const float*)d_in[0];
  const float* Wf  = (const float*)d_in[1];
  const float* bWf = (const float*)d_in[2];
  const float* Wi  = (const float*)d_in[3];
  const float* bWi = (const float*)d_in[4];
  const float* Wo  = (const float*)d_in[5];
  const float* bWo = (const float*)d_in[6];
  const float* Wc  = (const float*)d_in[7];
  const float* bWc = (const float*)d_in[8];
  const float* Uf  = (const float*)d_in[9];
  const float* bUf = (const float*)d_in[10];
  const float* Ui  = (const float*)d_in[11];
  const float* bUi = (const float*)d_in[12];
  const float* Uo  = (const float*)d_in[13];
  const float* bUo = (const float*)d_in[14];
  const float* Uc  = (const float*)d_in[15];
  const float* bUc = (const float*)d_in[16];

  char* ws = (char*)d_ws;
  unsigned short* xw   = (unsigned short*)(ws);                 // 134217728 B
  unsigned short* Wall = (unsigned short*)(ws + 134217728);     //   1048576 B
  unsigned short* Uall = (unsigned short*)(ws + 135266304);     //   2097152 B
  float*          ball = (float*)         (ws + 137363456);     //      8192 B
  unsigned short* hbuf = (unsigned short*)(ws + 137371648);     //    131072 B
  int*            flags= (int*)           (ws + 137502720);     //       256 B

  prep_kernel<<<768, 256, 0, stream>>>(Wf, bWf, Wi, bWi, Wo, bWo, Wc, bWc,
                                       Uf, bUf, Ui, bUi, Uo, bUo, Uc, bUc,
                                       Wall, Uall, ball, flags);
  xw_gemm<<<dim3(16, 256), 256, 0, stream>>>(x, Wall, ball, xw);
  lstm_scan<<<64, 256, 0, stream>>>(xw, Uall, hbuf, flags, (float*)d_out);
}

// Round 9
// 1824.907 us; speedup vs baseline: 1.5802x; 1.5802x over previous
//
#include <hip/hip_runtime.h>
#include <cstdint>
#include <cstddef>

// ---------------------------------------------------------------------------
// LSTM T=512 B=64 I=256 H=512  (fp32 in/out, bf16 MFMA compute)
//
// Phase A (prep):    pack Wall/Uall bf16, ball=bW+bU (f32), zero sync flags.
// Phase B (xw_gemm): xw[t*64+b][4H] = x @ Wall^T + ball, bf16 out.
// Phase C (scan):    64 persistent WGs = 4 batch-groups x 16 hidden-slices.
//                    U slice in VGPRs for all 512 steps. R0-proven handoff
//                    protocol (events byte-identical) + R7 hseq-after-publish.
//                    R9 delta (consumer only): PER-WAVE QUAD STAGING.
//                    Wave w spins on flags[4w..4w+3] (lanes 0..3, one flag
//                    each, s_sleep(1)) then stages h cols 128w..128w+128
//                    (16 rows x 128 cols, 64B/lane contiguous 8B atomic
//                    loads -- single-copy, same 16KB/WG/step as R0; R8's
//                    4x-redundant scatter is what killed it). Deletes the
//                    post-spin WG barrier (4 -> 3 barriers/step) and
//                    overlaps late-producer waits with staging of ready
//                    quads. In-order wave issue => stage loads cannot start
//                    before the spin's last flag load resolves;
//                    sched_barrier+memory clobber stops compiler hoisting.
//                    WAR: stage reads < gates barrier < drain barrier <
//                    publish, which gates peers' slot overwrites (R0 proof).
// ---------------------------------------------------------------------------

typedef __attribute__((ext_vector_type(8))) short short8;
typedef __attribute__((ext_vector_type(4))) float float4v;

__device__ __forceinline__ unsigned short f2bf(float f) {
  unsigned u = __float_as_uint(f);
  u = u + 0x7FFFu + ((u >> 16) & 1u);   // RNE
  return (unsigned short)(u >> 16);
}
__device__ __forceinline__ float bf2f(unsigned short s) {
  return __uint_as_float(((unsigned)s) << 16);
}
__device__ __forceinline__ unsigned long long pack4(float4 v) {
  return (unsigned long long)f2bf(v.x) |
         ((unsigned long long)f2bf(v.y) << 16) |
         ((unsigned long long)f2bf(v.z) << 32) |
         ((unsigned long long)f2bf(v.w) << 48);
}

// ------------------------------ Phase A ------------------------------------
__global__ void prep_kernel(
    const float* __restrict__ Wf, const float* __restrict__ bWf,
    const float* __restrict__ Wi, const float* __restrict__ bWi,
    const float* __restrict__ Wo, const float* __restrict__ bWo,
    const float* __restrict__ Wc, const float* __restrict__ bWc,
    const float* __restrict__ Uf, const float* __restrict__ bUf,
    const float* __restrict__ Ui, const float* __restrict__ bUi,
    const float* __restrict__ Uo, const float* __restrict__ bUo,
    const float* __restrict__ Uc, const float* __restrict__ bUc,
    unsigned short* __restrict__ Wall, unsigned short* __restrict__ Uall,
    float* __restrict__ ball, int* __restrict__ flags)
{
  const float* Ws[4]  = {Wf, Wi, Wo, Wc};
  const float* Us[4]  = {Uf, Ui, Uo, Uc};
  const float* bWs[4] = {bWf, bWi, bWo, bWc};
  const float* bUs[4] = {bUf, bUi, bUo, bUc};
  const long long NW4 = 131072;   // 2048*256/4
  const long long NU4 = 262144;   // 2048*512/4
  const long long NB4 = 512;      // 2048/4
  const long long TOT = NW4 + NU4 + NB4;
  long long idx0 = (long long)blockIdx.x * blockDim.x + threadIdx.x;
  if (idx0 < 64) flags[idx0] = 0;
  long long stride = (long long)gridDim.x * blockDim.x;
  for (long long u = idx0; u < TOT; u += stride) {
    if (u < NW4) {
      int e = (int)(u << 2);
      int n = e >> 8, k = e & 255;
      float4 v = *(const float4*)(Ws[n >> 9] + (size_t)(n & 511) * 256 + k);
      ((unsigned long long*)Wall)[u] = pack4(v);
    } else if (u < NW4 + NU4) {
      long long q = u - NW4;
      int e = (int)(q << 2);
      int n = e >> 9, k = e & 511;
      float4 v = *(const float4*)(Us[n >> 9] + (size_t)(n & 511) * 512 + k);
      ((unsigned long long*)Uall)[q] = pack4(v);
    } else {
      long long q = u - NW4 - NU4;
      int e = (int)(q << 2);
      int gate = e >> 9, r = e & 511;
      float4 a = *(const float4*)(bWs[gate] + r);
      float4 b = *(const float4*)(bUs[gate] + r);
      float4 sv;
      sv.x = a.x + b.x; sv.y = a.y + b.y; sv.z = a.z + b.z; sv.w = a.w + b.w;
      *(float4*)(ball + e) = sv;
    }
  }
}

// ------------------------------ Phase B ------------------------------------
// xw[m][n] = sum_k x[m][k]*Wall[n][k] + ball[n],  M=32768 N=2048 K=256.
// 128x128 tile, BK=64, 4 waves in 2x2, each wave 64x64 (16 accs).
__global__ __launch_bounds__(256, 2) void xw_gemm(
    const float* __restrict__ x,
    const unsigned short* __restrict__ Wall,
    const float* __restrict__ ball,
    unsigned short* __restrict__ xw)
{
  __shared__ short As[128 * 72];
  __shared__ short Bs[128 * 72];
  const int tid = threadIdx.x;
  const int bn = blockIdx.x, bm = blockIdx.y;
  const int Mbase = bm * 128, Nbase = bn * 128;
  const int w = tid >> 6, L = tid & 63, lq = L >> 4, lr = L & 15;
  const int wm = w >> 1, wn = w & 1;
  const int srow = tid >> 1, shalf = tid & 1;  // staging: 32 elems per thread

  float4v acc[4][4];
  #pragma unroll
  for (int a = 0; a < 4; ++a)
    #pragma unroll
    for (int b = 0; b < 4; ++b) acc[a][b] = (float4v){0.f, 0.f, 0.f, 0.f};

  for (int ko = 0; ko < 256; ko += 64) {
    const float* gaf = x + (size_t)(Mbase + srow) * 256 + ko + shalf * 32;
    float4 f0 = *(const float4*)(gaf);
    float4 f1 = *(const float4*)(gaf + 4);
    float4 f2 = *(const float4*)(gaf + 8);
    float4 f3 = *(const float4*)(gaf + 12);
    float4 f4 = *(const float4*)(gaf + 16);
    float4 f5 = *(const float4*)(gaf + 20);
    float4 f6 = *(const float4*)(gaf + 24);
    float4 f7 = *(const float4*)(gaf + 28);
    const unsigned short* gb = Wall + (size_t)(Nbase + srow) * 256 + ko + shalf * 32;
    short8 b0 = *(const short8*)(gb);
    short8 b1 = *(const short8*)(gb + 8);
    short8 b2 = *(const short8*)(gb + 16);
    short8 b3 = *(const short8*)(gb + 24);
    __syncthreads();  // protect previous iteration's LDS reads
    {
      unsigned long long* pa = (unsigned long long*)&As[srow * 72 + shalf * 32];
      pa[0] = pack4(f0); pa[1] = pack4(f1);
      pa[2] = pack4(f2); pa[3] = pack4(f3);
      pa[4] = pack4(f4); pa[5] = pack4(f5);
      pa[6] = pack4(f6); pa[7] = pack4(f7);
      short* pb = &Bs[srow * 72 + shalf * 32];
      *(short8*)(pb) = b0; *(short8*)(pb + 8) = b1;
      *(short8*)(pb + 16) = b2; *(short8*)(pb + 24) = b3;
    }
    __syncthreads();
    #pragma unroll
    for (int kk = 0; kk < 64; kk += 32) {
      short8 af[4], bfr[4];
      #pragma unroll
      for (int mi = 0; mi < 4; ++mi)
        af[mi] = *(const short8*)&As[(wm * 64 + mi * 16 + lr) * 72 + kk + lq * 8];
      #pragma unroll
      for (int ni = 0; ni < 4; ++ni)
        bfr[ni] = *(const short8*)&Bs[(wn * 64 + ni * 16 + lr) * 72 + kk + lq * 8];
      #pragma unroll
      for (int mi = 0; mi < 4; ++mi)
        #pragma unroll
        for (int ni = 0; ni < 4; ++ni)
          acc[mi][ni] = __builtin_amdgcn_mfma_f32_16x16x32_bf16(
              af[mi], bfr[ni], acc[mi][ni], 0, 0, 0);
    }
  }
  // epilogue: +bias, bf16 store
  #pragma unroll
  for (int ni = 0; ni < 4; ++ni) {
    int col = Nbase + wn * 64 + ni * 16 + lr;
    float bias = ball[col];
    #pragma unroll
    for (int mi = 0; mi < 4; ++mi) {
      #pragma unroll
      for (int r = 0; r < 4; ++r) {
        int row = Mbase + wm * 64 + mi * 16 + lq * 4 + r;
        xw[(size_t)row * 2048 + col] = f2bf(acc[mi][ni][r] + bias);
      }
    }
  }
}

// ------------------------------ Phase C ------------------------------------
// 64 WGs: g = wg>>4 (batch group, 16 rows), s = wg&15 (hidden slice, 32 cols).
// Wave w (0..3) = gate w (f,i,o,c): U rows w*512+s*32..+32 held in VGPRs.
// h handoff: relaxed agent atomics (L3-coherent); R0 protocol, R9 consumer.
__global__ __launch_bounds__(256, 1) void lstm_scan(
    const unsigned short* __restrict__ xw,
    const unsigned short* __restrict__ Uall,
    unsigned short* __restrict__ hbuf,   // [2][64][512] bf16
    int* __restrict__ flags,             // [4][16]
    float* __restrict__ out)
{
  __shared__ short hstage[16 * 520];          // h_{t-1} slice, padded rows
  __shared__ float gates[4 * 16 * 33];        // mfma gate outputs (f32)
  __shared__ unsigned short xwb[4 * 16 * 32]; // xw tile (bf16)

  const int tid = threadIdx.x;
  const int wg = blockIdx.x;
  const int g = wg >> 4;
  const int s = wg & 15;
  const int w = tid >> 6, L = tid & 63, lq = L >> 4, lr = L & 15;

  // elementwise ownership: (batch row eb, col pair ej, ej+1)
  const int eb = tid >> 4;
  const int ej = (tid & 15) * 2;
  // xw prefetch mapping: thread -> (batch xb, gate xg, 8-col chunk xc)
  const int xb = tid >> 4, xg = (tid >> 2) & 3, xc = tid & 3;
  // R9 staging map: wave w stages quad w (h cols 128w..128w+128);
  // lane L: row L>>2, 32-col chunk (L&3)*32 within the quad (64B contiguous).
  const int qrow = L >> 2;
  const int qoff = w * 128 + (L & 3) * 32;

  float* hseq = out;                                // T*B*H
  float* hfin = out + (size_t)512 * 64 * 512;
  float* cfin = hfin + (size_t)64 * 512;
  int* grp_flags = flags + g * 16;

  // --- U fragments into registers (held across the whole t-loop) ---
  short8 uf[2][16];
  #pragma unroll
  for (int nt = 0; nt < 2; ++nt)
    #pragma unroll
    for (int kt = 0; kt < 16; ++kt) {
      const unsigned short* p = Uall +
          (size_t)(w * 512 + s * 32 + nt * 16 + lr) * 512 + kt * 32 + lq * 8;
      uf[nt][kt] = *(const short8*)p;
    }

  float c0 = 0.f, c1 = 0.f, h0 = 0.f, h1 = 0.f;

  for (int t = 0; t < 512; ++t) {
    // prefetch xw for this step (overlaps the flag spin)
    const unsigned short* xp = xw +
        ((size_t)(t * 64 + g * 16 + xb)) * 2048 + xg * 512 + s * 32 + xc * 8;
    short8 xv = *(const short8*)xp;

    float4v a0a = (float4v){0.f, 0.f, 0.f, 0.f};
    float4v a0b = (float4v){0.f, 0.f, 0.f, 0.f};
    float4v a1a = (float4v){0.f, 0.f, 0.f, 0.f};
    float4v a1b = (float4v){0.f, 0.f, 0.f, 0.f};

    if (t > 0) {
      // per-wave spin: lanes 0..3 of wave w poll flags[4w+L] (16 spinners
      // total across the WG, same flag line + poll traffic as R0).
      if (L < 4) {
        while (__hip_atomic_load(&grp_flags[w * 4 + L], __ATOMIC_RELAXED,
                                 __HIP_MEMORY_SCOPE_AGENT) < t)
          __builtin_amdgcn_s_sleep(1);
      }
      // in-order wave issue: stage loads below cannot issue before the
      // spin's final flag load resolves; block compiler hoisting too.
      __builtin_amdgcn_sched_barrier(0);
      asm volatile("" ::: "memory");
      // stage quad w: 16 rows x 128 cols, 64B/lane contiguous (8x8B atomics)
      const unsigned short* hsrc =
          hbuf + ((size_t)((t - 1) & 1)) * 32768 + (size_t)g * 8192;
      const unsigned long long* p = (const unsigned long long*)
          (hsrc + (size_t)qrow * 512 + qoff);
      unsigned long long hv[8];
      #pragma unroll
      for (int r = 0; r < 8; ++r)
        hv[r] = __hip_atomic_load(p + r, __ATOMIC_RELAXED,
                                  __HIP_MEMORY_SCOPE_AGENT);
      {
        unsigned long long* q =
            (unsigned long long*)&hstage[qrow * 520 + qoff];
        #pragma unroll
        for (int r = 0; r < 8; ++r) q[r] = hv[r];
      }
      __syncthreads();   // all quads staged
      // 4 parallel dependency chains of 8 MFMAs each
      #pragma unroll
      for (int kt = 0; kt < 8; ++kt) {
        short8 afA = *(const short8*)&hstage[lr * 520 + kt * 32 + lq * 8];
        short8 afB = *(const short8*)&hstage[lr * 520 + (kt + 8) * 32 + lq * 8];
        a0a = __builtin_amdgcn_mfma_f32_16x16x32_bf16(afA, uf[0][kt], a0a, 0, 0, 0);
        a0b = __builtin_amdgcn_mfma_f32_16x16x32_bf16(afB, uf[0][kt + 8], a0b, 0, 0, 0);
        a1a = __builtin_amdgcn_mfma_f32_16x16x32_bf16(afA, uf[1][kt], a1a, 0, 0, 0);
        a1b = __builtin_amdgcn_mfma_f32_16x16x32_bf16(afB, uf[1][kt + 8], a1b, 0, 0, 0);
      }
    }
    float4v acc0 = a0a + a0b;
    float4v acc1 = a1a + a1b;

    // gate tile -> LDS (f32), xw tile -> LDS (bf16)
    #pragma unroll
    for (int r = 0; r < 4; ++r) {
      gates[w * 528 + (lq * 4 + r) * 33 + lr] = acc0[r];
      gates[w * 528 + (lq * 4 + r) * 33 + 16 + lr] = acc1[r];
    }
    *(short8*)&xwb[xg * 512 + xb * 32 + xc * 8] = xv;
    __syncthreads();

    // elementwise LSTM cell for (eb, ej) and (eb, ej+1)
    {
      float gf = gates[eb * 33 + ej] + bf2f(xwb[eb * 32 + ej]);
      float gi = gates[528 + eb * 33 + ej] + bf2f(xwb[512 + eb * 32 + ej]);
      float go = gates[1056 + eb * 33 + ej] + bf2f(xwb[1024 + eb * 32 + ej]);
      float gc = gates[1584 + eb * 33 + ej] + bf2f(xwb[1536 + eb * 32 + ej]);
      float f_ = 1.f / (1.f + __expf(-gf));
      float i_ = 1.f / (1.f + __expf(-gi));
      float o_ = 1.f / (1.f + __expf(-go));
      float ct = 1.f - 2.f / (__expf(2.f * gc) + 1.f);
      c0 = f_ * c0 + i_ * ct;
      h0 = o_ * (1.f - 2.f / (__expf(2.f * c0) + 1.f));
    }
    {
      int j = ej + 1;
      float gf = gates[eb * 33 + j] + bf2f(xwb[eb * 32 + j]);
      float gi = gates[528 + eb * 33 + j] + bf2f(xwb[512 + eb * 32 + j]);
      float go = gates[1056 + eb * 33 + j] + bf2f(xwb[1024 + eb * 32 + j]);
      float gc = gates[1584 + eb * 33 + j] + bf2f(xwb[1536 + eb * 32 + j]);
      float f_ = 1.f / (1.f + __expf(-gf));
      float i_ = 1.f / (1.f + __expf(-gi));
      float o_ = 1.f / (1.f + __expf(-go));
      float ct = 1.f - 2.f / (__expf(2.f * gc) + 1.f);
      c1 = f_ * c1 + i_ * ct;
      h1 = o_ * (1.f - 2.f / (__expf(2.f * c1) + 1.f));
    }
    // h handoff (coherent 4B atomic store to L3)
    unsigned hb = ((unsigned)f2bf(h1) << 16) | (unsigned)f2bf(h0);
    unsigned* hdst = (unsigned*)(hbuf + ((size_t)(t & 1)) * 32768 +
                                 ((size_t)(g * 16 + eb)) * 512 + s * 32 + ej);
    __hip_atomic_store(hdst, hb, __ATOMIC_RELAXED, __HIP_MEMORY_SCOPE_AGENT);

    __syncthreads();  // vmcnt(0) drain: all h stores at L3 before flag
    if (tid == 0)
      __hip_atomic_store(&grp_flags[s], t + 1, __ATOMIC_RELAXED,
                         __HIP_MEMORY_SCOPE_AGENT);

    // hseq out AFTER publish (never read in-kernel; retire overlaps spin)
    size_t orow = ((size_t)(t * 64 + g * 16 + eb)) * 512 + s * 32 + ej;
    {
      float2 hv2 = make_float2(h0, h1);
      __builtin_nontemporal_store(*(double*)&hv2, (double*)(hseq + orow));
    }
  }

  // final states
  size_t fo = ((size_t)(g * 16 + eb)) * 512 + s * 32 + ej;
  *(float2*)(hfin + fo) = make_float2(h0, h1);
  *(float2*)(cfin + fo) = make_float2(c0, c1);
}

// ------------------------------ launch -------------------------------------
extern "C" void kernel_launch(void* const* d_in, const int* in_sizes, int n_in,
                              void* d_out, int out_size, void* d_ws, size_t ws_size,
                              hipStream_t stream) {
  (void)in_sizes; (void)n_in; (void)out_size; (void)ws_size;
  const float* x   = (const float*)d_in[0];
  const float* Wf  = (const float*)d_in[1];
  const float* bWf = (const float*)d_in[2];
  const float* Wi  = (const float*)d_in[3];
  const float* bWi = (const float*)d_in[4];
  const float* Wo  = (const float*)d_in[5];
  const float* bWo = (const float*)d_in[6];
  const float* Wc  = (const float*)d_in[7];
  const float* bWc = (const float*)d_in[8];
  const float* Uf  = (const float*)d_in[9];
  const float* bUf = (const float*)d_in[10];
  const float* Ui  = (const float*)d_in[11];
  const float* bUi = (const float*)d_in[12];
  const float* Uo  = (const float*)d_in[13];
  const float* bUo = (const float*)d_in[14];
  const float* Uc  = (const float*)d_in[15];
  const float* bUc = (const float*)d_in[16];

  char* ws = (char*)d_ws;
  unsigned short* xw   = (unsigned short*)(ws);                 // 134217728 B
  unsigned short* Wall = (unsigned short*)(ws + 134217728);     //   1048576 B
  unsigned short* Uall = (unsigned short*)(ws + 135266304);     //   2097152 B
  float*          ball = (float*)         (ws + 137363456);     //      8192 B
  unsigned short* hbuf = (unsigned short*)(ws + 137371648);     //    131072 B
  int*            flags= (int*)           (ws + 137502720);     //       256 B

  prep_kernel<<<768, 256, 0, stream>>>(Wf, bWf, Wi, bWi, Wo, bWo, Wc, bWc,
                                       Uf, bUf, Ui, bUi, Uo, bUo, Uc, bUc,
                                       Wall, Uall, ball, flags);
  xw_gemm<<<dim3(16, 256), 256, 0, stream>>>(x, Wall, ball, xw);
  lstm_scan<<<64, 256, 0, stream>>>(xw, Uall, hbuf, flags, (float*)d_out);
}

// Round 10
// 1499.459 us; speedup vs baseline: 1.9232x; 1.2170x over previous
//
#include <hip/hip_runtime.h>
#include <cstdint>
#include <cstddef>

// ---------------------------------------------------------------------------
// LSTM T=512 B=64 I=256 H=512  (fp32 in/out, bf16 MFMA compute)
//
// Phase A (prep):    pack Wall/Uall bf16, ball=bW+bU (f32), zero sync flags.
// Phase B (xw_gemm): xw[t*64+b][4H] = x @ Wall^T + ball, bf16 out.
// Phase C (scan):    64 persistent WGs = 4 batch-groups x 16 hidden-slices.
//                    U slice in VGPRs for all 512 steps. R0-proven handoff
//                    (bf16 hbuf agent atomics, per-group 16-flag line,
//                    16-thread spin, barrier-drained tid0 publish) --
//                    every structural variant tried in R1/R2/R3/R8/R9 lost.
//                    Kept: R7 hseq-after-publish (best total 1510.6us).
//                    R10 delta (single micro-knob): spin is busy-poll (no
//                    s_sleep) -- removes the ~64cy sleep quantum from the
//                    flag-detect leg. Traffic level unchanged (16 lanes/WG
//                    polling one 64B line, R0-validated).
// ---------------------------------------------------------------------------

typedef __attribute__((ext_vector_type(8))) short short8;
typedef __attribute__((ext_vector_type(4))) float float4v;

__device__ __forceinline__ unsigned short f2bf(float f) {
  unsigned u = __float_as_uint(f);
  u = u + 0x7FFFu + ((u >> 16) & 1u);   // RNE
  return (unsigned short)(u >> 16);
}
__device__ __forceinline__ float bf2f(unsigned short s) {
  return __uint_as_float(((unsigned)s) << 16);
}
__device__ __forceinline__ unsigned long long pack4(float4 v) {
  return (unsigned long long)f2bf(v.x) |
         ((unsigned long long)f2bf(v.y) << 16) |
         ((unsigned long long)f2bf(v.z) << 32) |
         ((unsigned long long)f2bf(v.w) << 48);
}

// ------------------------------ Phase A ------------------------------------
__global__ void prep_kernel(
    const float* __restrict__ Wf, const float* __restrict__ bWf,
    const float* __restrict__ Wi, const float* __restrict__ bWi,
    const float* __restrict__ Wo, const float* __restrict__ bWo,
    const float* __restrict__ Wc, const float* __restrict__ bWc,
    const float* __restrict__ Uf, const float* __restrict__ bUf,
    const float* __restrict__ Ui, const float* __restrict__ bUi,
    const float* __restrict__ Uo, const float* __restrict__ bUo,
    const float* __restrict__ Uc, const float* __restrict__ bUc,
    unsigned short* __restrict__ Wall, unsigned short* __restrict__ Uall,
    float* __restrict__ ball, int* __restrict__ flags)
{
  const float* Ws[4]  = {Wf, Wi, Wo, Wc};
  const float* Us[4]  = {Uf, Ui, Uo, Uc};
  const float* bWs[4] = {bWf, bWi, bWo, bWc};
  const float* bUs[4] = {bUf, bUi, bUo, bUc};
  const long long NW4 = 131072;   // 2048*256/4
  const long long NU4 = 262144;   // 2048*512/4
  const long long NB4 = 512;      // 2048/4
  const long long TOT = NW4 + NU4 + NB4;
  long long idx0 = (long long)blockIdx.x * blockDim.x + threadIdx.x;
  if (idx0 < 64) flags[idx0] = 0;
  long long stride = (long long)gridDim.x * blockDim.x;
  for (long long u = idx0; u < TOT; u += stride) {
    if (u < NW4) {
      int e = (int)(u << 2);
      int n = e >> 8, k = e & 255;
      float4 v = *(const float4*)(Ws[n >> 9] + (size_t)(n & 511) * 256 + k);
      ((unsigned long long*)Wall)[u] = pack4(v);
    } else if (u < NW4 + NU4) {
      long long q = u - NW4;
      int e = (int)(q << 2);
      int n = e >> 9, k = e & 511;
      float4 v = *(const float4*)(Us[n >> 9] + (size_t)(n & 511) * 512 + k);
      ((unsigned long long*)Uall)[q] = pack4(v);
    } else {
      long long q = u - NW4 - NU4;
      int e = (int)(q << 2);
      int gate = e >> 9, r = e & 511;
      float4 a = *(const float4*)(bWs[gate] + r);
      float4 b = *(const float4*)(bUs[gate] + r);
      float4 sv;
      sv.x = a.x + b.x; sv.y = a.y + b.y; sv.z = a.z + b.z; sv.w = a.w + b.w;
      *(float4*)(ball + e) = sv;
    }
  }
}

// ------------------------------ Phase B ------------------------------------
// xw[m][n] = sum_k x[m][k]*Wall[n][k] + ball[n],  M=32768 N=2048 K=256.
// 128x128 tile, BK=64, 4 waves in 2x2, each wave 64x64 (16 accs).
__global__ __launch_bounds__(256, 2) void xw_gemm(
    const float* __restrict__ x,
    const unsigned short* __restrict__ Wall,
    const float* __restrict__ ball,
    unsigned short* __restrict__ xw)
{
  __shared__ short As[128 * 72];
  __shared__ short Bs[128 * 72];
  const int tid = threadIdx.x;
  const int bn = blockIdx.x, bm = blockIdx.y;
  const int Mbase = bm * 128, Nbase = bn * 128;
  const int w = tid >> 6, L = tid & 63, lq = L >> 4, lr = L & 15;
  const int wm = w >> 1, wn = w & 1;
  const int srow = tid >> 1, shalf = tid & 1;  // staging: 32 elems per thread

  float4v acc[4][4];
  #pragma unroll
  for (int a = 0; a < 4; ++a)
    #pragma unroll
    for (int b = 0; b < 4; ++b) acc[a][b] = (float4v){0.f, 0.f, 0.f, 0.f};

  for (int ko = 0; ko < 256; ko += 64) {
    const float* gaf = x + (size_t)(Mbase + srow) * 256 + ko + shalf * 32;
    float4 f0 = *(const float4*)(gaf);
    float4 f1 = *(const float4*)(gaf + 4);
    float4 f2 = *(const float4*)(gaf + 8);
    float4 f3 = *(const float4*)(gaf + 12);
    float4 f4 = *(const float4*)(gaf + 16);
    float4 f5 = *(const float4*)(gaf + 20);
    float4 f6 = *(const float4*)(gaf + 24);
    float4 f7 = *(const float4*)(gaf + 28);
    const unsigned short* gb = Wall + (size_t)(Nbase + srow) * 256 + ko + shalf * 32;
    short8 b0 = *(const short8*)(gb);
    short8 b1 = *(const short8*)(gb + 8);
    short8 b2 = *(const short8*)(gb + 16);
    short8 b3 = *(const short8*)(gb + 24);
    __syncthreads();  // protect previous iteration's LDS reads
    {
      unsigned long long* pa = (unsigned long long*)&As[srow * 72 + shalf * 32];
      pa[0] = pack4(f0); pa[1] = pack4(f1);
      pa[2] = pack4(f2); pa[3] = pack4(f3);
      pa[4] = pack4(f4); pa[5] = pack4(f5);
      pa[6] = pack4(f6); pa[7] = pack4(f7);
      short* pb = &Bs[srow * 72 + shalf * 32];
      *(short8*)(pb) = b0; *(short8*)(pb + 8) = b1;
      *(short8*)(pb + 16) = b2; *(short8*)(pb + 24) = b3;
    }
    __syncthreads();
    #pragma unroll
    for (int kk = 0; kk < 64; kk += 32) {
      short8 af[4], bfr[4];
      #pragma unroll
      for (int mi = 0; mi < 4; ++mi)
        af[mi] = *(const short8*)&As[(wm * 64 + mi * 16 + lr) * 72 + kk + lq * 8];
      #pragma unroll
      for (int ni = 0; ni < 4; ++ni)
        bfr[ni] = *(const short8*)&Bs[(wn * 64 + ni * 16 + lr) * 72 + kk + lq * 8];
      #pragma unroll
      for (int mi = 0; mi < 4; ++mi)
        #pragma unroll
        for (int ni = 0; ni < 4; ++ni)
          acc[mi][ni] = __builtin_amdgcn_mfma_f32_16x16x32_bf16(
              af[mi], bfr[ni], acc[mi][ni], 0, 0, 0);
    }
  }
  // epilogue: +bias, bf16 store
  #pragma unroll
  for (int ni = 0; ni < 4; ++ni) {
    int col = Nbase + wn * 64 + ni * 16 + lr;
    float bias = ball[col];
    #pragma unroll
    for (int mi = 0; mi < 4; ++mi) {
      #pragma unroll
      for (int r = 0; r < 4; ++r) {
        int row = Mbase + wm * 64 + mi * 16 + lq * 4 + r;
        xw[(size_t)row * 2048 + col] = f2bf(acc[mi][ni][r] + bias);
      }
    }
  }
}

// ------------------------------ Phase C ------------------------------------
// 64 WGs: g = wg>>4 (batch group, 16 rows), s = wg&15 (hidden slice, 32 cols).
// Wave w (0..3) = gate w (f,i,o,c): U rows w*512+s*32..+32 held in VGPRs.
// h handoff: relaxed agent atomics (L3-coherent, no fences).
__global__ __launch_bounds__(256, 1) void lstm_scan(
    const unsigned short* __restrict__ xw,
    const unsigned short* __restrict__ Uall,
    unsigned short* __restrict__ hbuf,   // [2][64][512] bf16
    int* __restrict__ flags,             // [4][16]
    float* __restrict__ out)
{
  __shared__ short hstage[16 * 520];          // h_{t-1} slice, padded rows
  __shared__ float gates[4 * 16 * 33];        // mfma gate outputs (f32)
  __shared__ unsigned short xwb[4 * 16 * 32]; // xw tile (bf16)

  const int tid = threadIdx.x;
  const int wg = blockIdx.x;
  const int g = wg >> 4;
  const int s = wg & 15;
  const int w = tid >> 6, L = tid & 63, lq = L >> 4, lr = L & 15;

  // elementwise ownership: (batch row eb, col pair ej, ej+1)
  const int eb = tid >> 4;
  const int ej = (tid & 15) * 2;
  // xw prefetch mapping: thread -> (batch xb, gate xg, 8-col chunk xc)
  const int xb = tid >> 4, xg = (tid >> 2) & 3, xc = tid & 3;

  float* hseq = out;                                // T*B*H
  float* hfin = out + (size_t)512 * 64 * 512;
  float* cfin = hfin + (size_t)64 * 512;
  int* grp_flags = flags + g * 16;

  // --- U fragments into registers (held across the whole t-loop) ---
  short8 uf[2][16];
  #pragma unroll
  for (int nt = 0; nt < 2; ++nt)
    #pragma unroll
    for (int kt = 0; kt < 16; ++kt) {
      const unsigned short* p = Uall +
          (size_t)(w * 512 + s * 32 + nt * 16 + lr) * 512 + kt * 32 + lq * 8;
      uf[nt][kt] = *(const short8*)p;
    }

  float c0 = 0.f, c1 = 0.f, h0 = 0.f, h1 = 0.f;

  for (int t = 0; t < 512; ++t) {
    // prefetch xw for this step (overlaps the flag spin)
    const unsigned short* xp = xw +
        ((size_t)(t * 64 + g * 16 + xb)) * 2048 + xg * 512 + s * 32 + xc * 8;
    short8 xv = *(const short8*)xp;

    float4v a0a = (float4v){0.f, 0.f, 0.f, 0.f};
    float4v a0b = (float4v){0.f, 0.f, 0.f, 0.f};
    float4v a1a = (float4v){0.f, 0.f, 0.f, 0.f};
    float4v a1b = (float4v){0.f, 0.f, 0.f, 0.f};

    if (t > 0) {
      // busy-poll spin (no s_sleep): removes the ~64cy sleep quantum from
      // the detect leg; 16 lanes/WG on one 64B flag line (R0 traffic level).
      if (tid < 16) {
        while (__hip_atomic_load(&grp_flags[tid], __ATOMIC_RELAXED,
                                 __HIP_MEMORY_SCOPE_AGENT) < t) { }
      }
      __syncthreads();
      // stage h_{t-1} (16x512 bf16) -> LDS via coherent 8B atomic loads
      const unsigned short* hsrc =
          hbuf + ((size_t)((t - 1) & 1)) * 32768 + (size_t)g * 8192;
      const int scol = (tid & 63) * 8;
      const int sr0 = tid >> 6;
      unsigned long long hv[8];
      #pragma unroll
      for (int r = 0; r < 4; ++r) {
        const unsigned long long* p = (const unsigned long long*)
            (hsrc + (size_t)(sr0 + r * 4) * 512 + scol);
        hv[2 * r]     = __hip_atomic_load(p, __ATOMIC_RELAXED,
                                          __HIP_MEMORY_SCOPE_AGENT);
        hv[2 * r + 1] = __hip_atomic_load(p + 1, __ATOMIC_RELAXED,
                                          __HIP_MEMORY_SCOPE_AGENT);
      }
      #pragma unroll
      for (int r = 0; r < 4; ++r) {
        unsigned long long* q =
            (unsigned long long*)&hstage[(sr0 + r * 4) * 520 + scol];
        q[0] = hv[2 * r]; q[1] = hv[2 * r + 1];
      }
      __syncthreads();
      // 4 parallel dependency chains of 8 MFMAs each
      #pragma unroll
      for (int kt = 0; kt < 8; ++kt) {
        short8 afA = *(const short8*)&hstage[lr * 520 + kt * 32 + lq * 8];
        short8 afB = *(const short8*)&hstage[lr * 520 + (kt + 8) * 32 + lq * 8];
        a0a = __builtin_amdgcn_mfma_f32_16x16x32_bf16(afA, uf[0][kt], a0a, 0, 0, 0);
        a0b = __builtin_amdgcn_mfma_f32_16x16x32_bf16(afB, uf[0][kt + 8], a0b, 0, 0, 0);
        a1a = __builtin_amdgcn_mfma_f32_16x16x32_bf16(afA, uf[1][kt], a1a, 0, 0, 0);
        a1b = __builtin_amdgcn_mfma_f32_16x16x32_bf16(afB, uf[1][kt + 8], a1b, 0, 0, 0);
      }
    }
    float4v acc0 = a0a + a0b;
    float4v acc1 = a1a + a1b;

    // gate tile -> LDS (f32), xw tile -> LDS (bf16)
    #pragma unroll
    for (int r = 0; r < 4; ++r) {
      gates[w * 528 + (lq * 4 + r) * 33 + lr] = acc0[r];
      gates[w * 528 + (lq * 4 + r) * 33 + 16 + lr] = acc1[r];
    }
    *(short8*)&xwb[xg * 512 + xb * 32 + xc * 8] = xv;
    __syncthreads();

    // elementwise LSTM cell for (eb, ej) and (eb, ej+1)
    {
      float gf = gates[eb * 33 + ej] + bf2f(xwb[eb * 32 + ej]);
      float gi = gates[528 + eb * 33 + ej] + bf2f(xwb[512 + eb * 32 + ej]);
      float go = gates[1056 + eb * 33 + ej] + bf2f(xwb[1024 + eb * 32 + ej]);
      float gc = gates[1584 + eb * 33 + ej] + bf2f(xwb[1536 + eb * 32 + ej]);
      float f_ = 1.f / (1.f + __expf(-gf));
      float i_ = 1.f / (1.f + __expf(-gi));
      float o_ = 1.f / (1.f + __expf(-go));
      float ct = 1.f - 2.f / (__expf(2.f * gc) + 1.f);
      c0 = f_ * c0 + i_ * ct;
      h0 = o_ * (1.f - 2.f / (__expf(2.f * c0) + 1.f));
    }
    {
      int j = ej + 1;
      float gf = gates[eb * 33 + j] + bf2f(xwb[eb * 32 + j]);
      float gi = gates[528 + eb * 33 + j] + bf2f(xwb[512 + eb * 32 + j]);
      float go = gates[1056 + eb * 33 + j] + bf2f(xwb[1024 + eb * 32 + j]);
      float gc = gates[1584 + eb * 33 + j] + bf2f(xwb[1536 + eb * 32 + j]);
      float f_ = 1.f / (1.f + __expf(-gf));
      float i_ = 1.f / (1.f + __expf(-gi));
      float o_ = 1.f / (1.f + __expf(-go));
      float ct = 1.f - 2.f / (__expf(2.f * gc) + 1.f);
      c1 = f_ * c1 + i_ * ct;
      h1 = o_ * (1.f - 2.f / (__expf(2.f * c1) + 1.f));
    }
    // h handoff (coherent 4B atomic store to L3)
    unsigned hb = ((unsigned)f2bf(h1) << 16) | (unsigned)f2bf(h0);
    unsigned* hdst = (unsigned*)(hbuf + ((size_t)(t & 1)) * 32768 +
                                 ((size_t)(g * 16 + eb)) * 512 + s * 32 + ej);
    __hip_atomic_store(hdst, hb, __ATOMIC_RELAXED, __HIP_MEMORY_SCOPE_AGENT);

    __syncthreads();  // vmcnt(0) drain: all h stores at L3 before flag
    if (tid == 0)
      __hip_atomic_store(&grp_flags[s], t + 1, __ATOMIC_RELAXED,
                         __HIP_MEMORY_SCOPE_AGENT);

    // hseq out AFTER publish (never read in-kernel; retire overlaps spin)
    size_t orow = ((size_t)(t * 64 + g * 16 + eb)) * 512 + s * 32 + ej;
    {
      float2 hv2 = make_float2(h0, h1);
      __builtin_nontemporal_store(*(double*)&hv2, (double*)(hseq + orow));
    }
  }

  // final states
  size_t fo = ((size_t)(g * 16 + eb)) * 512 + s * 32 + ej;
  *(float2*)(hfin + fo) = make_float2(h0, h1);
  *(float2*)(cfin + fo) = make_float2(c0, c1);
}

// ------------------------------ launch -------------------------------------
extern "C" void kernel_launch(void* const* d_in, const int* in_sizes, int n_in,
                              void* d_out, int out_size, void* d_ws, size_t ws_size,
                              hipStream_t stream) {
  (void)in_sizes; (void)n_in; (void)out_size; (void)ws_size;
  const float* x   = (const float*)d_in[0];
  const float* Wf  = (const float*)d_in[1];
  const float* bWf = (const float*)d_in[2];
  const float* Wi  = (const float*)d_in[3];
  const float* bWi = (const float*)d_in[4];
  const float* Wo  = (const float*)d_in[5];
  const float* bWo = (const float*)d_in[6];
  const float* Wc  = (const float*)d_in[7];
  const float* bWc = (const float*)d_in[8];
  const float* Uf  = (const float*)d_in[9];
  const float* bUf = (const float*)d_in[10];
  const float* Ui  = (const float*)d_in[11];
  const float* bUi = (const float*)d_in[12];
  const float* Uo  = (const float*)d_in[13];
  const float* bUo = (const float*)d_in[14];
  const float* Uc  = (const float*)d_in[15];
  const float* bUc = (const float*)d_in[16];

  char* ws = (char*)d_ws;
  unsigned short* xw   = (unsigned short*)(ws);                 // 134217728 B
  unsigned short* Wall = (unsigned short*)(ws + 134217728);     //   1048576 B
  unsigned short* Uall = (unsigned short*)(ws + 135266304);     //   2097152 B
  float*          ball = (float*)         (ws + 137363456);     //      8192 B
  unsigned short* hbuf = (unsigned short*)(ws + 137371648);     //    131072 B
  int*            flags= (int*)           (ws + 137502720);     //       256 B

  prep_kernel<<<768, 256, 0, stream>>>(Wf, bWf, Wi, bWi, Wo, bWo, Wc, bWc,
                                       Uf, bUf, Ui, bUi, Uo, bUo, Uc, bUc,
                                       Wall, Uall, ball, flags);
  xw_gemm<<<dim3(16, 256), 256, 0, stream>>>(x, Wall, ball, xw);
  lstm_scan<<<64, 256, 0, stream>>>(xw, Uall, hbuf, flags, (float*)d_out);
}

// Round 11
// 1485.943 us; speedup vs baseline: 1.9407x; 1.0091x over previous
//
#include <hip/hip_runtime.h>
#include <cstdint>
#include <cstddef>

// ---------------------------------------------------------------------------
// LSTM T=512 B=64 I=256 H=512  (fp32 in/out, bf16 MFMA compute)
//
// Phase A (prep):    pack Wall/Uall bf16, ball=bW+bU (f32), zero sync flags,
//                    and (if workspace permits) convert x -> xb16 once, so
//                    the GEMM's A-staging needs zero conversion VALU.
// Phase B (xw_gemm): xw[t*64+b][4H] = x @ Wall^T + ball, bf16 out.
//                    PRE variant stages A from xb16 (4x short8 loads, like
//                    B) -- removes the per-ko f32 loads + ~48 pack4 VALU ops
//                    per thread that made staging VALU-bound. Fallback
//                    variant (small ws) is the R10 fused-convert GEMM.
//                    Results bit-identical (same RNE pack in prep).
// Phase C (scan):    R10-verbatim (best measured: 1499.5us total).
//                    64 persistent WGs = 4 batch-groups x 16 hidden-slices;
//                    U slice in VGPRs; R0-proven handoff (bf16 hbuf agent
//                    atomics, per-group 16-flag line, 16-thread busy-poll,
//                    barrier-drained tid0 publish); hseq stored after
//                    publish (R7). Scan is at its structural latency floor:
//                    ~6350cy/step = serial {store-ack, flag RT, h-load RT,
//                    MFMA+elementwise} chain; 8 variants all lost or tied.
// ---------------------------------------------------------------------------

typedef __attribute__((ext_vector_type(8))) short short8;
typedef __attribute__((ext_vector_type(4))) float float4v;

__device__ __forceinline__ unsigned short f2bf(float f) {
  unsigned u = __float_as_uint(f);
  u = u + 0x7FFFu + ((u >> 16) & 1u);   // RNE
  return (unsigned short)(u >> 16);
}
__device__ __forceinline__ float bf2f(unsigned short s) {
  return __uint_as_float(((unsigned)s) << 16);
}
__device__ __forceinline__ unsigned long long pack4(float4 v) {
  return (unsigned long long)f2bf(v.x) |
         ((unsigned long long)f2bf(v.y) << 16) |
         ((unsigned long long)f2bf(v.z) << 32) |
         ((unsigned long long)f2bf(v.w) << 48);
}

// ------------------------------ Phase A ------------------------------------
__global__ void prep_kernel(
    const float* __restrict__ Wf, const float* __restrict__ bWf,
    const float* __restrict__ Wi, const float* __restrict__ bWi,
    const float* __restrict__ Wo, const float* __restrict__ bWo,
    const float* __restrict__ Wc, const float* __restrict__ bWc,
    const float* __restrict__ Uf, const float* __restrict__ bUf,
    const float* __restrict__ Ui, const float* __restrict__ bUi,
    const float* __restrict__ Uo, const float* __restrict__ bUo,
    const float* __restrict__ Uc, const float* __restrict__ bUc,
    unsigned short* __restrict__ Wall, unsigned short* __restrict__ Uall,
    float* __restrict__ ball, int* __restrict__ flags,
    const float* __restrict__ x, unsigned short* __restrict__ xb16,
    int do_x)
{
  const float* Ws[4]  = {Wf, Wi, Wo, Wc};
  const float* Us[4]  = {Uf, Ui, Uo, Uc};
  const float* bWs[4] = {bWf, bWi, bWo, bWc};
  const float* bUs[4] = {bUf, bUi, bUo, bUc};
  const long long NW4 = 131072;   // 2048*256/4
  const long long NU4 = 262144;   // 2048*512/4
  const long long NB4 = 512;      // 2048/4
  const long long NX4 = do_x ? 2097152 : 0;   // 32768*256/4
  const long long TOT = NW4 + NU4 + NB4 + NX4;
  long long idx0 = (long long)blockIdx.x * blockDim.x + threadIdx.x;
  if (idx0 < 64) flags[idx0] = 0;
  long long stride = (long long)gridDim.x * blockDim.x;
  for (long long u = idx0; u < TOT; u += stride) {
    if (u < NW4) {
      int e = (int)(u << 2);
      int n = e >> 8, k = e & 255;
      float4 v = *(const float4*)(Ws[n >> 9] + (size_t)(n & 511) * 256 + k);
      ((unsigned long long*)Wall)[u] = pack4(v);
    } else if (u < NW4 + NU4) {
      long long q = u - NW4;
      int e = (int)(q << 2);
      int n = e >> 9, k = e & 511;
      float4 v = *(const float4*)(Us[n >> 9] + (size_t)(n & 511) * 512 + k);
      ((unsigned long long*)Uall)[q] = pack4(v);
    } else if (u < NW4 + NU4 + NB4) {
      long long q = u - NW4 - NU4;
      int e = (int)(q << 2);
      int gate = e >> 9, r = e & 511;
      float4 a = *(const float4*)(bWs[gate] + r);
      float4 b = *(const float4*)(bUs[gate] + r);
      float4 sv;
      sv.x = a.x + b.x; sv.y = a.y + b.y; sv.z = a.z + b.z; sv.w = a.w + b.w;
      *(float4*)(ball + e) = sv;
    } else {
      long long q = u - NW4 - NU4 - NB4;
      float4 v = ((const float4*)x)[q];
      ((unsigned long long*)xb16)[q] = pack4(v);
    }
  }
}

// ------------------------- Phase B (PRE variant) ---------------------------
// A staged from pre-converted xb16: symmetric with B, zero conversion VALU.
__global__ __launch_bounds__(256, 2) void xw_gemm_pre(
    const unsigned short* __restrict__ xb16,
    const unsigned short* __restrict__ Wall,
    const float* __restrict__ ball,
    unsigned short* __restrict__ xw)
{
  __shared__ short As[128 * 72];
  __shared__ short Bs[128 * 72];
  const int tid = threadIdx.x;
  const int bn = blockIdx.x, bm = blockIdx.y;
  const int Mbase = bm * 128, Nbase = bn * 128;
  const int w = tid >> 6, L = tid & 63, lq = L >> 4, lr = L & 15;
  const int wm = w >> 1, wn = w & 1;
  const int srow = tid >> 1, shalf = tid & 1;  // staging: 32 elems per thread

  float4v acc[4][4];
  #pragma unroll
  for (int a = 0; a < 4; ++a)
    #pragma unroll
    for (int b = 0; b < 4; ++b) acc[a][b] = (float4v){0.f, 0.f, 0.f, 0.f};

  for (int ko = 0; ko < 256; ko += 64) {
    const unsigned short* ga = xb16 + (size_t)(Mbase + srow) * 256 + ko + shalf * 32;
    short8 a0 = *(const short8*)(ga);
    short8 a1 = *(const short8*)(ga + 8);
    short8 a2 = *(const short8*)(ga + 16);
    short8 a3 = *(const short8*)(ga + 24);
    const unsigned short* gb = Wall + (size_t)(Nbase + srow) * 256 + ko + shalf * 32;
    short8 b0 = *(const short8*)(gb);
    short8 b1 = *(const short8*)(gb + 8);
    short8 b2 = *(const short8*)(gb + 16);
    short8 b3 = *(const short8*)(gb + 24);
    __syncthreads();  // protect previous iteration's LDS reads
    {
      short* pa = &As[srow * 72 + shalf * 32];
      *(short8*)(pa) = a0; *(short8*)(pa + 8) = a1;
      *(short8*)(pa + 16) = a2; *(short8*)(pa + 24) = a3;
      short* pb = &Bs[srow * 72 + shalf * 32];
      *(short8*)(pb) = b0; *(short8*)(pb + 8) = b1;
      *(short8*)(pb + 16) = b2; *(short8*)(pb + 24) = b3;
    }
    __syncthreads();
    #pragma unroll
    for (int kk = 0; kk < 64; kk += 32) {
      short8 af[4], bfr[4];
      #pragma unroll
      for (int mi = 0; mi < 4; ++mi)
        af[mi] = *(const short8*)&As[(wm * 64 + mi * 16 + lr) * 72 + kk + lq * 8];
      #pragma unroll
      for (int ni = 0; ni < 4; ++ni)
        bfr[ni] = *(const short8*)&Bs[(wn * 64 + ni * 16 + lr) * 72 + kk + lq * 8];
      #pragma unroll
      for (int mi = 0; mi < 4; ++mi)
        #pragma unroll
        for (int ni = 0; ni < 4; ++ni)
          acc[mi][ni] = __builtin_amdgcn_mfma_f32_16x16x32_bf16(
              af[mi], bfr[ni], acc[mi][ni], 0, 0, 0);
    }
  }
  // epilogue: +bias, bf16 store
  #pragma unroll
  for (int ni = 0; ni < 4; ++ni) {
    int col = Nbase + wn * 64 + ni * 16 + lr;
    float bias = ball[col];
    #pragma unroll
    for (int mi = 0; mi < 4; ++mi) {
      #pragma unroll
      for (int r = 0; r < 4; ++r) {
        int row = Mbase + wm * 64 + mi * 16 + lq * 4 + r;
        xw[(size_t)row * 2048 + col] = f2bf(acc[mi][ni][r] + bias);
      }
    }
  }
}

// ----------------------- Phase B (fallback variant) ------------------------
// Fused f32->bf16 conversion in A-staging (R10-verbatim); used when ws is
// too small for xb16.
__global__ __launch_bounds__(256, 2) void xw_gemm(
    const float* __restrict__ x,
    const unsigned short* __restrict__ Wall,
    const float* __restrict__ ball,
    unsigned short* __restrict__ xw)
{
  __shared__ short As[128 * 72];
  __shared__ short Bs[128 * 72];
  const int tid = threadIdx.x;
  const int bn = blockIdx.x, bm = blockIdx.y;
  const int Mbase = bm * 128, Nbase = bn * 128;
  const int w = tid >> 6, L = tid & 63, lq = L >> 4, lr = L & 15;
  const int wm = w >> 1, wn = w & 1;
  const int srow = tid >> 1, shalf = tid & 1;

  float4v acc[4][4];
  #pragma unroll
  for (int a = 0; a < 4; ++a)
    #pragma unroll
    for (int b = 0; b < 4; ++b) acc[a][b] = (float4v){0.f, 0.f, 0.f, 0.f};

  for (int ko = 0; ko < 256; ko += 64) {
    const float* gaf = x + (size_t)(Mbase + srow) * 256 + ko + shalf * 32;
    float4 f0 = *(const float4*)(gaf);
    float4 f1 = *(const float4*)(gaf + 4);
    float4 f2 = *(const float4*)(gaf + 8);
    float4 f3 = *(const float4*)(gaf + 12);
    float4 f4 = *(const float4*)(gaf + 16);
    float4 f5 = *(const float4*)(gaf + 20);
    float4 f6 = *(const float4*)(gaf + 24);
    float4 f7 = *(const float4*)(gaf + 28);
    const unsigned short* gb = Wall + (size_t)(Nbase + srow) * 256 + ko + shalf * 32;
    short8 b0 = *(const short8*)(gb);
    short8 b1 = *(const short8*)(gb + 8);
    short8 b2 = *(const short8*)(gb + 16);
    short8 b3 = *(const short8*)(gb + 24);
    __syncthreads();
    {
      unsigned long long* pa = (unsigned long long*)&As[srow * 72 + shalf * 32];
      pa[0] = pack4(f0); pa[1] = pack4(f1);
      pa[2] = pack4(f2); pa[3] = pack4(f3);
      pa[4] = pack4(f4); pa[5] = pack4(f5);
      pa[6] = pack4(f6); pa[7] = pack4(f7);
      short* pb = &Bs[srow * 72 + shalf * 32];
      *(short8*)(pb) = b0; *(short8*)(pb + 8) = b1;
      *(short8*)(pb + 16) = b2; *(short8*)(pb + 24) = b3;
    }
    __syncthreads();
    #pragma unroll
    for (int kk = 0; kk < 64; kk += 32) {
      short8 af[4], bfr[4];
      #pragma unroll
      for (int mi = 0; mi < 4; ++mi)
        af[mi] = *(const short8*)&As[(wm * 64 + mi * 16 + lr) * 72 + kk + lq * 8];
      #pragma unroll
      for (int ni = 0; ni < 4; ++ni)
        bfr[ni] = *(const short8*)&Bs[(wn * 64 + ni * 16 + lr) * 72 + kk + lq * 8];
      #pragma unroll
      for (int mi = 0; mi < 4; ++mi)
        #pragma unroll
        for (int ni = 0; ni < 4; ++ni)
          acc[mi][ni] = __builtin_amdgcn_mfma_f32_16x16x32_bf16(
              af[mi], bfr[ni], acc[mi][ni], 0, 0, 0);
    }
  }
  #pragma unroll
  for (int ni = 0; ni < 4; ++ni) {
    int col = Nbase + wn * 64 + ni * 16 + lr;
    float bias = ball[col];
    #pragma unroll
    for (int mi = 0; mi < 4; ++mi) {
      #pragma unroll
      for (int r = 0; r < 4; ++r) {
        int row = Mbase + wm * 64 + mi * 16 + lq * 4 + r;
        xw[(size_t)row * 2048 + col] = f2bf(acc[mi][ni][r] + bias);
      }
    }
  }
}

// ------------------------------ Phase C ------------------------------------
// R10-verbatim. 64 WGs: g = wg>>4 (batch group), s = wg&15 (hidden slice).
// Wave w (0..3) = gate w (f,i,o,c): U rows w*512+s*32..+32 held in VGPRs.
__global__ __launch_bounds__(256, 1) void lstm_scan(
    const unsigned short* __restrict__ xw,
    const unsigned short* __restrict__ Uall,
    unsigned short* __restrict__ hbuf,   // [2][64][512] bf16
    int* __restrict__ flags,             // [4][16]
    float* __restrict__ out)
{
  __shared__ short hstage[16 * 520];          // h_{t-1} slice, padded rows
  __shared__ float gates[4 * 16 * 33];        // mfma gate outputs (f32)
  __shared__ unsigned short xwb[4 * 16 * 32]; // xw tile (bf16)

  const int tid = threadIdx.x;
  const int wg = blockIdx.x;
  const int g = wg >> 4;
  const int s = wg & 15;
  const int w = tid >> 6, L = tid & 63, lq = L >> 4, lr = L & 15;

  // elementwise ownership: (batch row eb, col pair ej, ej+1)
  const int eb = tid >> 4;
  const int ej = (tid & 15) * 2;
  // xw prefetch mapping: thread -> (batch xb, gate xg, 8-col chunk xc)
  const int xb = tid >> 4, xg = (tid >> 2) & 3, xc = tid & 3;

  float* hseq = out;                                // T*B*H
  float* hfin = out + (size_t)512 * 64 * 512;
  float* cfin = hfin + (size_t)64 * 512;
  int* grp_flags = flags + g * 16;

  // --- U fragments into registers (held across the whole t-loop) ---
  short8 uf[2][16];
  #pragma unroll
  for (int nt = 0; nt < 2; ++nt)
    #pragma unroll
    for (int kt = 0; kt < 16; ++kt) {
      const unsigned short* p = Uall +
          (size_t)(w * 512 + s * 32 + nt * 16 + lr) * 512 + kt * 32 + lq * 8;
      uf[nt][kt] = *(const short8*)p;
    }

  float c0 = 0.f, c1 = 0.f, h0 = 0.f, h1 = 0.f;

  for (int t = 0; t < 512; ++t) {
    // prefetch xw for this step (overlaps the flag spin)
    const unsigned short* xp = xw +
        ((size_t)(t * 64 + g * 16 + xb)) * 2048 + xg * 512 + s * 32 + xc * 8;
    short8 xv = *(const short8*)xp;

    float4v a0a = (float4v){0.f, 0.f, 0.f, 0.f};
    float4v a0b = (float4v){0.f, 0.f, 0.f, 0.f};
    float4v a1a = (float4v){0.f, 0.f, 0.f, 0.f};
    float4v a1b = (float4v){0.f, 0.f, 0.f, 0.f};

    if (t > 0) {
      // busy-poll spin: 16 lanes/WG on one 64B flag line
      if (tid < 16) {
        while (__hip_atomic_load(&grp_flags[tid], __ATOMIC_RELAXED,
                                 __HIP_MEMORY_SCOPE_AGENT) < t) { }
      }
      __syncthreads();
      // stage h_{t-1} (16x512 bf16) -> LDS via coherent 8B atomic loads
      const unsigned short* hsrc =
          hbuf + ((size_t)((t - 1) & 1)) * 32768 + (size_t)g * 8192;
      const int scol = (tid & 63) * 8;
      const int sr0 = tid >> 6;
      unsigned long long hv[8];
      #pragma unroll
      for (int r = 0; r < 4; ++r) {
        const unsigned long long* p = (const unsigned long long*)
            (hsrc + (size_t)(sr0 + r * 4) * 512 + scol);
        hv[2 * r]     = __hip_atomic_load(p, __ATOMIC_RELAXED,
                                          __HIP_MEMORY_SCOPE_AGENT);
        hv[2 * r + 1] = __hip_atomic_load(p + 1, __ATOMIC_RELAXED,
                                          __HIP_MEMORY_SCOPE_AGENT);
      }
      #pragma unroll
      for (int r = 0; r < 4; ++r) {
        unsigned long long* q =
            (unsigned long long*)&hstage[(sr0 + r * 4) * 520 + scol];
        q[0] = hv[2 * r]; q[1] = hv[2 * r + 1];
      }
      __syncthreads();
      // 4 parallel dependency chains of 8 MFMAs each
      #pragma unroll
      for (int kt = 0; kt < 8; ++kt) {
        short8 afA = *(const short8*)&hstage[lr * 520 + kt * 32 + lq * 8];
        short8 afB = *(const short8*)&hstage[lr * 520 + (kt + 8) * 32 + lq * 8];
        a0a = __builtin_amdgcn_mfma_f32_16x16x32_bf16(afA, uf[0][kt], a0a, 0, 0, 0);
        a0b = __builtin_amdgcn_mfma_f32_16x16x32_bf16(afB, uf[0][kt + 8], a0b, 0, 0, 0);
        a1a = __builtin_amdgcn_mfma_f32_16x16x32_bf16(afA, uf[1][kt], a1a, 0, 0, 0);
        a1b = __builtin_amdgcn_mfma_f32_16x16x32_bf16(afB, uf[1][kt + 8], a1b, 0, 0, 0);
      }
    }
    float4v acc0 = a0a + a0b;
    float4v acc1 = a1a + a1b;

    // gate tile -> LDS (f32), xw tile -> LDS (bf16)
    #pragma unroll
    for (int r = 0; r < 4; ++r) {
      gates[w * 528 + (lq * 4 + r) * 33 + lr] = acc0[r];
      gates[w * 528 + (lq * 4 + r) * 33 + 16 + lr] = acc1[r];
    }
    *(short8*)&xwb[xg * 512 + xb * 32 + xc * 8] = xv;
    __syncthreads();

    // elementwise LSTM cell for (eb, ej) and (eb, ej+1)
    {
      float gf = gates[eb * 33 + ej] + bf2f(xwb[eb * 32 + ej]);
      float gi = gates[528 + eb * 33 + ej] + bf2f(xwb[512 + eb * 32 + ej]);
      float go = gates[1056 + eb * 33 + ej] + bf2f(xwb[1024 + eb * 32 + ej]);
      float gc = gates[1584 + eb * 33 + ej] + bf2f(xwb[1536 + eb * 32 + ej]);
      float f_ = 1.f / (1.f + __expf(-gf));
      float i_ = 1.f / (1.f + __expf(-gi));
      float o_ = 1.f / (1.f + __expf(-go));
      float ct = 1.f - 2.f / (__expf(2.f * gc) + 1.f);
      c0 = f_ * c0 + i_ * ct;
      h0 = o_ * (1.f - 2.f / (__expf(2.f * c0) + 1.f));
    }
    {
      int j = ej + 1;
      float gf = gates[eb * 33 + j] + bf2f(xwb[eb * 32 + j]);
      float gi = gates[528 + eb * 33 + j] + bf2f(xwb[512 + eb * 32 + j]);
      float go = gates[1056 + eb * 33 + j] + bf2f(xwb[1024 + eb * 32 + j]);
      float gc = gates[1584 + eb * 33 + j] + bf2f(xwb[1536 + eb * 32 + j]);
      float f_ = 1.f / (1.f + __expf(-gf));
      float i_ = 1.f / (1.f + __expf(-gi));
      float o_ = 1.f / (1.f + __expf(-go));
      float ct = 1.f - 2.f / (__expf(2.f * gc) + 1.f);
      c1 = f_ * c1 + i_ * ct;
      h1 = o_ * (1.f - 2.f / (__expf(2.f * c1) + 1.f));
    }
    // h handoff (coherent 4B atomic store to L3)
    unsigned hb = ((unsigned)f2bf(h1) << 16) | (unsigned)f2bf(h0);
    unsigned* hdst = (unsigned*)(hbuf + ((size_t)(t & 1)) * 32768 +
                                 ((size_t)(g * 16 + eb)) * 512 + s * 32 + ej);
    __hip_atomic_store(hdst, hb, __ATOMIC_RELAXED, __HIP_MEMORY_SCOPE_AGENT);

    __syncthreads();  // vmcnt(0) drain: all h stores at L3 before flag
    if (tid == 0)
      __hip_atomic_store(&grp_flags[s], t + 1, __ATOMIC_RELAXED,
                         __HIP_MEMORY_SCOPE_AGENT);

    // hseq out AFTER publish (never read in-kernel; retire overlaps spin)
    size_t orow = ((size_t)(t * 64 + g * 16 + eb)) * 512 + s * 32 + ej;
    {
      float2 hv2 = make_float2(h0, h1);
      __builtin_nontemporal_store(*(double*)&hv2, (double*)(hseq + orow));
    }
  }

  // final states
  size_t fo = ((size_t)(g * 16 + eb)) * 512 + s * 32 + ej;
  *(float2*)(hfin + fo) = make_float2(h0, h1);
  *(float2*)(cfin + fo) = make_float2(c0, c1);
}

// ------------------------------ launch -------------------------------------
extern "C" void kernel_launch(void* const* d_in, const int* in_sizes, int n_in,
                              void* d_out, int out_size, void* d_ws, size_t ws_size,
                              hipStream_t stream) {
  (void)in_sizes; (void)n_in; (void)out_size;
  const float* x   = (const float*)d_in[0];
  const float* Wf  = (const float*)d_in[1];
  const float* bWf = (const float*)d_in[2];
  const float* Wi  = (const float*)d_in[3];
  const float* bWi = (const float*)d_in[4];
  const float* Wo  = (const float*)d_in[5];
  const float* bWo = (const float*)d_in[6];
  const float* Wc  = (const float*)d_in[7];
  const float* bWc = (const float*)d_in[8];
  const float* Uf  = (const float*)d_in[9];
  const float* bUf = (const float*)d_in[10];
  const float* Ui  = (const float*)d_in[11];
  const float* bUi = (const float*)d_in[12];
  const float* Uo  = (const float*)d_in[13];
  const float* bUo = (const float*)d_in[14];
  const float* Uc  = (const float*)d_in[15];
  const float* bUc = (const float*)d_in[16];

  char* ws = (char*)d_ws;
  unsigned short* xw   = (unsigned short*)(ws);                 // 134217728 B
  unsigned short* Wall = (unsigned short*)(ws + 134217728);     //   1048576 B
  unsigned short* Uall = (unsigned short*)(ws + 135266304);     //   2097152 B
  float*          ball = (float*)         (ws + 137363456);     //      8192 B
  unsigned short* hbuf = (unsigned short*)(ws + 137371648);     //    131072 B
  int*            flags= (int*)           (ws + 137502720);     //      1024 B
  unsigned short* xb16 = (unsigned short*)(ws + 137503744);     //  16777216 B

  const int pre = (ws_size >= (size_t)137503744 + 16777216) ? 1 : 0;

  prep_kernel<<<768, 256, 0, stream>>>(Wf, bWf, Wi, bWi, Wo, bWo, Wc, bWc,
                                       Uf, bUf, Ui, bUi, Uo, bUo, Uc, bUc,
                                       Wall, Uall, ball, flags, x, xb16, pre);
  if (pre)
    xw_gemm_pre<<<dim3(16, 256), 256, 0, stream>>>(xb16, Wall, ball, xw);
  else
    xw_gemm<<<dim3(16, 256), 256, 0, stream>>>(x, Wall, ball, xw);
  lstm_scan<<<64, 256, 0, stream>>>(xw, Uall, hbuf, flags, (float*)d_out);
}

// Round 12
// 1456.173 us; speedup vs baseline: 1.9804x; 1.0204x over previous
//
#include <hip/hip_runtime.h>
#include <cstdint>
#include <cstddef>

// ---------------------------------------------------------------------------
// LSTM T=512 B=64 I=256 H=512  (fp32 in/out, bf16 MFMA compute)
//
// Phase A (prep):    pack Wall/Uall bf16, ball=bW+bU (f32), zero sync flags,
//                    convert x -> xb16 once (ws-guarded).
// Phase B (xw_gemm): xw[t*64+b][4H] = x @ Wall^T + ball, bf16 out.
//                    PRE variant (R11): A staged from xb16, zero conversion
//                    VALU. R12 delta: COALESCED EPILOGUE -- bias+pack C-tile
//                    into LDS (reusing As/Bs space behind a barrier), then
//                    8x16B stores/thread (256B-contiguous per-16-lane
//                    segments) instead of 64x2B scattered stores.
// Phase C (scan):    R10-verbatim (scan floor: ~1350us). 64 persistent WGs;
//                    U slice in VGPRs; R0-proven handoff (bf16 hbuf agent
//                    atomics, per-group 16-flag line, 16-thread busy-poll,
//                    barrier-drained tid0 publish); hseq stored after publish.
// ---------------------------------------------------------------------------

typedef __attribute__((ext_vector_type(8))) short short8;
typedef __attribute__((ext_vector_type(4))) float float4v;

__device__ __forceinline__ unsigned short f2bf(float f) {
  unsigned u = __float_as_uint(f);
  u = u + 0x7FFFu + ((u >> 16) & 1u);   // RNE
  return (unsigned short)(u >> 16);
}
__device__ __forceinline__ float bf2f(unsigned short s) {
  return __uint_as_float(((unsigned)s) << 16);
}
__device__ __forceinline__ unsigned long long pack4(float4 v) {
  return (unsigned long long)f2bf(v.x) |
         ((unsigned long long)f2bf(v.y) << 16) |
         ((unsigned long long)f2bf(v.z) << 32) |
         ((unsigned long long)f2bf(v.w) << 48);
}

// ------------------------------ Phase A ------------------------------------
__global__ void prep_kernel(
    const float* __restrict__ Wf, const float* __restrict__ bWf,
    const float* __restrict__ Wi, const float* __restrict__ bWi,
    const float* __restrict__ Wo, const float* __restrict__ bWo,
    const float* __restrict__ Wc, const float* __restrict__ bWc,
    const float* __restrict__ Uf, const float* __restrict__ bUf,
    const float* __restrict__ Ui, const float* __restrict__ bUi,
    const float* __restrict__ Uo, const float* __restrict__ bUo,
    const float* __restrict__ Uc, const float* __restrict__ bUc,
    unsigned short* __restrict__ Wall, unsigned short* __restrict__ Uall,
    float* __restrict__ ball, int* __restrict__ flags,
    const float* __restrict__ x, unsigned short* __restrict__ xb16,
    int do_x)
{
  const float* Ws[4]  = {Wf, Wi, Wo, Wc};
  const float* Us[4]  = {Uf, Ui, Uo, Uc};
  const float* bWs[4] = {bWf, bWi, bWo, bWc};
  const float* bUs[4] = {bUf, bUi, bUo, bUc};
  const long long NW4 = 131072;   // 2048*256/4
  const long long NU4 = 262144;   // 2048*512/4
  const long long NB4 = 512;      // 2048/4
  const long long NX4 = do_x ? 2097152 : 0;   // 32768*256/4
  const long long TOT = NW4 + NU4 + NB4 + NX4;
  long long idx0 = (long long)blockIdx.x * blockDim.x + threadIdx.x;
  if (idx0 < 64) flags[idx0] = 0;
  long long stride = (long long)gridDim.x * blockDim.x;
  for (long long u = idx0; u < TOT; u += stride) {
    if (u < NW4) {
      int e = (int)(u << 2);
      int n = e >> 8, k = e & 255;
      float4 v = *(const float4*)(Ws[n >> 9] + (size_t)(n & 511) * 256 + k);
      ((unsigned long long*)Wall)[u] = pack4(v);
    } else if (u < NW4 + NU4) {
      long long q = u - NW4;
      int e = (int)(q << 2);
      int n = e >> 9, k = e & 511;
      float4 v = *(const float4*)(Us[n >> 9] + (size_t)(n & 511) * 512 + k);
      ((unsigned long long*)Uall)[q] = pack4(v);
    } else if (u < NW4 + NU4 + NB4) {
      long long q = u - NW4 - NU4;
      int e = (int)(q << 2);
      int gate = e >> 9, r = e & 511;
      float4 a = *(const float4*)(bWs[gate] + r);
      float4 b = *(const float4*)(bUs[gate] + r);
      float4 sv;
      sv.x = a.x + b.x; sv.y = a.y + b.y; sv.z = a.z + b.z; sv.w = a.w + b.w;
      *(float4*)(ball + e) = sv;
    } else {
      long long q = u - NW4 - NU4 - NB4;
      float4 v = ((const float4*)x)[q];
      ((unsigned long long*)xb16)[q] = pack4(v);
    }
  }
}

// ------------------------- Phase B (PRE variant) ---------------------------
// A staged from pre-converted xb16; R12 coalesced epilogue via LDS C-stage.
__global__ __launch_bounds__(256, 2) void xw_gemm_pre(
    const unsigned short* __restrict__ xb16,
    const unsigned short* __restrict__ Wall,
    const float* __restrict__ ball,
    unsigned short* __restrict__ xw)
{
  __shared__ union {
    struct { short As[128 * 72]; short Bs[128 * 72]; } ab;   // 36864 B
    short cs[128 * 132];                                     // 33792 B
  } sm;
  const int tid = threadIdx.x;
  const int bn = blockIdx.x, bm = blockIdx.y;
  const int Mbase = bm * 128, Nbase = bn * 128;
  const int w = tid >> 6, L = tid & 63, lq = L >> 4, lr = L & 15;
  const int wm = w >> 1, wn = w & 1;
  const int srow = tid >> 1, shalf = tid & 1;  // staging: 32 elems per thread

  float4v acc[4][4];
  #pragma unroll
  for (int a = 0; a < 4; ++a)
    #pragma unroll
    for (int b = 0; b < 4; ++b) acc[a][b] = (float4v){0.f, 0.f, 0.f, 0.f};

  for (int ko = 0; ko < 256; ko += 64) {
    const unsigned short* ga = xb16 + (size_t)(Mbase + srow) * 256 + ko + shalf * 32;
    short8 a0 = *(const short8*)(ga);
    short8 a1 = *(const short8*)(ga + 8);
    short8 a2 = *(const short8*)(ga + 16);
    short8 a3 = *(const short8*)(ga + 24);
    const unsigned short* gb = Wall + (size_t)(Nbase + srow) * 256 + ko + shalf * 32;
    short8 b0 = *(const short8*)(gb);
    short8 b1 = *(const short8*)(gb + 8);
    short8 b2 = *(const short8*)(gb + 16);
    short8 b3 = *(const short8*)(gb + 24);
    __syncthreads();  // protect previous iteration's LDS reads
    {
      short* pa = &sm.ab.As[srow * 72 + shalf * 32];
      *(short8*)(pa) = a0; *(short8*)(pa + 8) = a1;
      *(short8*)(pa + 16) = a2; *(short8*)(pa + 24) = a3;
      short* pb = &sm.ab.Bs[srow * 72 + shalf * 32];
      *(short8*)(pb) = b0; *(short8*)(pb + 8) = b1;
      *(short8*)(pb + 16) = b2; *(short8*)(pb + 24) = b3;
    }
    __syncthreads();
    #pragma unroll
    for (int kk = 0; kk < 64; kk += 32) {
      short8 af[4], bfr[4];
      #pragma unroll
      for (int mi = 0; mi < 4; ++mi)
        af[mi] = *(const short8*)&sm.ab.As[(wm * 64 + mi * 16 + lr) * 72 + kk + lq * 8];
      #pragma unroll
      for (int ni = 0; ni < 4; ++ni)
        bfr[ni] = *(const short8*)&sm.ab.Bs[(wn * 64 + ni * 16 + lr) * 72 + kk + lq * 8];
      #pragma unroll
      for (int mi = 0; mi < 4; ++mi)
        #pragma unroll
        for (int ni = 0; ni < 4; ++ni)
          acc[mi][ni] = __builtin_amdgcn_mfma_f32_16x16x32_bf16(
              af[mi], bfr[ni], acc[mi][ni], 0, 0, 0);
    }
  }
  // ---- R12 epilogue: bias + bf16 pack -> LDS, then coalesced 16B stores ----
  __syncthreads();   // all MFMA LDS reads complete before As/Bs reuse
  #pragma unroll
  for (int ni = 0; ni < 4; ++ni) {
    int col = wn * 64 + ni * 16 + lr;
    float bias = ball[Nbase + col];
    #pragma unroll
    for (int mi = 0; mi < 4; ++mi) {
      #pragma unroll
      for (int r = 0; r < 4; ++r) {
        int row = wm * 64 + mi * 16 + lq * 4 + r;
        sm.cs[row * 132 + col] = (short)f2bf(acc[mi][ni][r] + bias);
      }
    }
  }
  __syncthreads();
  {
    const int crow0 = tid >> 4;          // 0..15
    const int ccol = (tid & 15) * 8;     // 0..120 (8 bf16 = 16 B)
    #pragma unroll
    for (int p = 0; p < 8; ++p) {
      int row = p * 16 + crow0;
      short8 v = *(const short8*)&sm.cs[row * 132 + ccol];
      *(short8*)(xw + (size_t)(Mbase + row) * 2048 + Nbase + ccol) = v;
    }
  }
}

// ----------------------- Phase B (fallback variant) ------------------------
// Fused f32->bf16 conversion in A-staging; used when ws is too small.
__global__ __launch_bounds__(256, 2) void xw_gemm(
    const float* __restrict__ x,
    const unsigned short* __restrict__ Wall,
    const float* __restrict__ ball,
    unsigned short* __restrict__ xw)
{
  __shared__ short As[128 * 72];
  __shared__ short Bs[128 * 72];
  const int tid = threadIdx.x;
  const int bn = blockIdx.x, bm = blockIdx.y;
  const int Mbase = bm * 128, Nbase = bn * 128;
  const int w = tid >> 6, L = tid & 63, lq = L >> 4, lr = L & 15;
  const int wm = w >> 1, wn = w & 1;
  const int srow = tid >> 1, shalf = tid & 1;

  float4v acc[4][4];
  #pragma unroll
  for (int a = 0; a < 4; ++a)
    #pragma unroll
    for (int b = 0; b < 4; ++b) acc[a][b] = (float4v){0.f, 0.f, 0.f, 0.f};

  for (int ko = 0; ko < 256; ko += 64) {
    const float* gaf = x + (size_t)(Mbase + srow) * 256 + ko + shalf * 32;
    float4 f0 = *(const float4*)(gaf);
    float4 f1 = *(const float4*)(gaf + 4);
    float4 f2 = *(const float4*)(gaf + 8);
    float4 f3 = *(const float4*)(gaf + 12);
    float4 f4 = *(const float4*)(gaf + 16);
    float4 f5 = *(const float4*)(gaf + 20);
    float4 f6 = *(const float4*)(gaf + 24);
    float4 f7 = *(const float4*)(gaf + 28);
    const unsigned short* gb = Wall + (size_t)(Nbase + srow) * 256 + ko + shalf * 32;
    short8 b0 = *(const short8*)(gb);
    short8 b1 = *(const short8*)(gb + 8);
    short8 b2 = *(const short8*)(gb + 16);
    short8 b3 = *(const short8*)(gb + 24);
    __syncthreads();
    {
      unsigned long long* pa = (unsigned long long*)&As[srow * 72 + shalf * 32];
      pa[0] = pack4(f0); pa[1] = pack4(f1);
      pa[2] = pack4(f2); pa[3] = pack4(f3);
      pa[4] = pack4(f4); pa[5] = pack4(f5);
      pa[6] = pack4(f6); pa[7] = pack4(f7);
      short* pb = &Bs[srow * 72 + shalf * 32];
      *(short8*)(pb) = b0; *(short8*)(pb + 8) = b1;
      *(short8*)(pb + 16) = b2; *(short8*)(pb + 24) = b3;
    }
    __syncthreads();
    #pragma unroll
    for (int kk = 0; kk < 64; kk += 32) {
      short8 af[4], bfr[4];
      #pragma unroll
      for (int mi = 0; mi < 4; ++mi)
        af[mi] = *(const short8*)&As[(wm * 64 + mi * 16 + lr) * 72 + kk + lq * 8];
      #pragma unroll
      for (int ni = 0; ni < 4; ++ni)
        bfr[ni] = *(const short8*)&Bs[(wn * 64 + ni * 16 + lr) * 72 + kk + lq * 8];
      #pragma unroll
      for (int mi = 0; mi < 4; ++mi)
        #pragma unroll
        for (int ni = 0; ni < 4; ++ni)
          acc[mi][ni] = __builtin_amdgcn_mfma_f32_16x16x32_bf16(
              af[mi], bfr[ni], acc[mi][ni], 0, 0, 0);
    }
  }
  #pragma unroll
  for (int ni = 0; ni < 4; ++ni) {
    int col = Nbase + wn * 64 + ni * 16 + lr;
    float bias = ball[col];
    #pragma unroll
    for (int mi = 0; mi < 4; ++mi) {
      #pragma unroll
      for (int r = 0; r < 4; ++r) {
        int row = Mbase + wm * 64 + mi * 16 + lq * 4 + r;
        xw[(size_t)row * 2048 + col] = f2bf(acc[mi][ni][r] + bias);
      }
    }
  }
}

// ------------------------------ Phase C ------------------------------------
// R10-verbatim. 64 WGs: g = wg>>4 (batch group), s = wg&15 (hidden slice).
// Wave w (0..3) = gate w (f,i,o,c): U rows w*512+s*32..+32 held in VGPRs.
__global__ __launch_bounds__(256, 1) void lstm_scan(
    const unsigned short* __restrict__ xw,
    const unsigned short* __restrict__ Uall,
    unsigned short* __restrict__ hbuf,   // [2][64][512] bf16
    int* __restrict__ flags,             // [4][16]
    float* __restrict__ out)
{
  __shared__ short hstage[16 * 520];          // h_{t-1} slice, padded rows
  __shared__ float gates[4 * 16 * 33];        // mfma gate outputs (f32)
  __shared__ unsigned short xwb[4 * 16 * 32]; // xw tile (bf16)

  const int tid = threadIdx.x;
  const int wg = blockIdx.x;
  const int g = wg >> 4;
  const int s = wg & 15;
  const int w = tid >> 6, L = tid & 63, lq = L >> 4, lr = L & 15;

  // elementwise ownership: (batch row eb, col pair ej, ej+1)
  const int eb = tid >> 4;
  const int ej = (tid & 15) * 2;
  // xw prefetch mapping: thread -> (batch xb, gate xg, 8-col chunk xc)
  const int xb = tid >> 4, xg = (tid >> 2) & 3, xc = tid & 3;

  float* hseq = out;                                // T*B*H
  float* hfin = out + (size_t)512 * 64 * 512;
  float* cfin = hfin + (size_t)64 * 512;
  int* grp_flags = flags + g * 16;

  // --- U fragments into registers (held across the whole t-loop) ---
  short8 uf[2][16];
  #pragma unroll
  for (int nt = 0; nt < 2; ++nt)
    #pragma unroll
    for (int kt = 0; kt < 16; ++kt) {
      const unsigned short* p = Uall +
          (size_t)(w * 512 + s * 32 + nt * 16 + lr) * 512 + kt * 32 + lq * 8;
      uf[nt][kt] = *(const short8*)p;
    }

  float c0 = 0.f, c1 = 0.f, h0 = 0.f, h1 = 0.f;

  for (int t = 0; t < 512; ++t) {
    // prefetch xw for this step (overlaps the flag spin)
    const unsigned short* xp = xw +
        ((size_t)(t * 64 + g * 16 + xb)) * 2048 + xg * 512 + s * 32 + xc * 8;
    short8 xv = *(const short8*)xp;

    float4v a0a = (float4v){0.f, 0.f, 0.f, 0.f};
    float4v a0b = (float4v){0.f, 0.f, 0.f, 0.f};
    float4v a1a = (float4v){0.f, 0.f, 0.f, 0.f};
    float4v a1b = (float4v){0.f, 0.f, 0.f, 0.f};

    if (t > 0) {
      // busy-poll spin: 16 lanes/WG on one 64B flag line
      if (tid < 16) {
        while (__hip_atomic_load(&grp_flags[tid], __ATOMIC_RELAXED,
                                 __HIP_MEMORY_SCOPE_AGENT) < t) { }
      }
      __syncthreads();
      // stage h_{t-1} (16x512 bf16) -> LDS via coherent 8B atomic loads
      const unsigned short* hsrc =
          hbuf + ((size_t)((t - 1) & 1)) * 32768 + (size_t)g * 8192;
      const int scol = (tid & 63) * 8;
      const int sr0 = tid >> 6;
      unsigned long long hv[8];
      #pragma unroll
      for (int r = 0; r < 4; ++r) {
        const unsigned long long* p = (const unsigned long long*)
            (hsrc + (size_t)(sr0 + r * 4) * 512 + scol);
        hv[2 * r]     = __hip_atomic_load(p, __ATOMIC_RELAXED,
                                          __HIP_MEMORY_SCOPE_AGENT);
        hv[2 * r + 1] = __hip_atomic_load(p + 1, __ATOMIC_RELAXED,
                                          __HIP_MEMORY_SCOPE_AGENT);
      }
      #pragma unroll
      for (int r = 0; r < 4; ++r) {
        unsigned long long* q =
            (unsigned long long*)&hstage[(sr0 + r * 4) * 520 + scol];
        q[0] = hv[2 * r]; q[1] = hv[2 * r + 1];
      }
      __syncthreads();
      // 4 parallel dependency chains of 8 MFMAs each
      #pragma unroll
      for (int kt = 0; kt < 8; ++kt) {
        short8 afA = *(const short8*)&hstage[lr * 520 + kt * 32 + lq * 8];
        short8 afB = *(const short8*)&hstage[lr * 520 + (kt + 8) * 32 + lq * 8];
        a0a = __builtin_amdgcn_mfma_f32_16x16x32_bf16(afA, uf[0][kt], a0a, 0, 0, 0);
        a0b = __builtin_amdgcn_mfma_f32_16x16x32_bf16(afB, uf[0][kt + 8], a0b, 0, 0, 0);
        a1a = __builtin_amdgcn_mfma_f32_16x16x32_bf16(afA, uf[1][kt], a1a, 0, 0, 0);
        a1b = __builtin_amdgcn_mfma_f32_16x16x32_bf16(afB, uf[1][kt + 8], a1b, 0, 0, 0);
      }
    }
    float4v acc0 = a0a + a0b;
    float4v acc1 = a1a + a1b;

    // gate tile -> LDS (f32), xw tile -> LDS (bf16)
    #pragma unroll
    for (int r = 0; r < 4; ++r) {
      gates[w * 528 + (lq * 4 + r) * 33 + lr] = acc0[r];
      gates[w * 528 + (lq * 4 + r) * 33 + 16 + lr] = acc1[r];
    }
    *(short8*)&xwb[xg * 512 + xb * 32 + xc * 8] = xv;
    __syncthreads();

    // elementwise LSTM cell for (eb, ej) and (eb, ej+1)
    {
      float gf = gates[eb * 33 + ej] + bf2f(xwb[eb * 32 + ej]);
      float gi = gates[528 + eb * 33 + ej] + bf2f(xwb[512 + eb * 32 + ej]);
      float go = gates[1056 + eb * 33 + ej] + bf2f(xwb[1024 + eb * 32 + ej]);
      float gc = gates[1584 + eb * 33 + ej] + bf2f(xwb[1536 + eb * 32 + ej]);
      float f_ = 1.f / (1.f + __expf(-gf));
      float i_ = 1.f / (1.f + __expf(-gi));
      float o_ = 1.f / (1.f + __expf(-go));
      float ct = 1.f - 2.f / (__expf(2.f * gc) + 1.f);
      c0 = f_ * c0 + i_ * ct;
      h0 = o_ * (1.f - 2.f / (__expf(2.f * c0) + 1.f));
    }
    {
      int j = ej + 1;
      float gf = gates[eb * 33 + j] + bf2f(xwb[eb * 32 + j]);
      float gi = gates[528 + eb * 33 + j] + bf2f(xwb[512 + eb * 32 + j]);
      float go = gates[1056 + eb * 33 + j] + bf2f(xwb[1024 + eb * 32 + j]);
      float gc = gates[1584 + eb * 33 + j] + bf2f(xwb[1536 + eb * 32 + j]);
      float f_ = 1.f / (1.f + __expf(-gf));
      float i_ = 1.f / (1.f + __expf(-gi));
      float o_ = 1.f / (1.f + __expf(-go));
      float ct = 1.f - 2.f / (__expf(2.f * gc) + 1.f);
      c1 = f_ * c1 + i_ * ct;
      h1 = o_ * (1.f - 2.f / (__expf(2.f * c1) + 1.f));
    }
    // h handoff (coherent 4B atomic store to L3)
    unsigned hb = ((unsigned)f2bf(h1) << 16) | (unsigned)f2bf(h0);
    unsigned* hdst = (unsigned*)(hbuf + ((size_t)(t & 1)) * 32768 +
                                 ((size_t)(g * 16 + eb)) * 512 + s * 32 + ej);
    __hip_atomic_store(hdst, hb, __ATOMIC_RELAXED, __HIP_MEMORY_SCOPE_AGENT);

    __syncthreads();  // vmcnt(0) drain: all h stores at L3 before flag
    if (tid == 0)
      __hip_atomic_store(&grp_flags[s], t + 1, __ATOMIC_RELAXED,
                         __HIP_MEMORY_SCOPE_AGENT);

    // hseq out AFTER publish (never read in-kernel; retire overlaps spin)
    size_t orow = ((size_t)(t * 64 + g * 16 + eb)) * 512 + s * 32 + ej;
    {
      float2 hv2 = make_float2(h0, h1);
      __builtin_nontemporal_store(*(double*)&hv2, (double*)(hseq + orow));
    }
  }

  // final states
  size_t fo = ((size_t)(g * 16 + eb)) * 512 + s * 32 + ej;
  *(float2*)(hfin + fo) = make_float2(h0, h1);
  *(float2*)(cfin + fo) = make_float2(c0, c1);
}

// ------------------------------ launch -------------------------------------
extern "C" void kernel_launch(void* const* d_in, const int* in_sizes, int n_in,
                              void* d_out, int out_size, void* d_ws, size_t ws_size,
                              hipStream_t stream) {
  (void)in_sizes; (void)n_in; (void)out_size;
  const float* x   = (const float*)d_in[0];
  const float* Wf  = (const float*)d_in[1];
  const float* bWf = (const float*)d_in[2];
  const float* Wi  = (const float*)d_in[3];
  const float* bWi = (const float*)d_in[4];
  const float* Wo  = (const float*)d_in[5];
  const float* bWo = (const float*)d_in[6];
  const float* Wc  = (const float*)d_in[7];
  const float* bWc = (const float*)d_in[8];
  const float* Uf  = (const float*)d_in[9];
  const float* bUf = (const float*)d_in[10];
  const float* Ui  = (const float*)d_in[11];
  const float* bUi = (const float*)d_in[12];
  const float* Uo  = (const float*)d_in[13];
  const float* bUo = (const float*)d_in[14];
  const float* Uc  = (const float*)d_in[15];
  const float* bUc = (const float*)d_in[16];

  char* ws = (char*)d_ws;
  unsigned short* xw   = (unsigned short*)(ws);                 // 134217728 B
  unsigned short* Wall = (unsigned short*)(ws + 134217728);     //   1048576 B
  unsigned short* Uall = (unsigned short*)(ws + 135266304);     //   2097152 B
  float*          ball = (float*)         (ws + 137363456);     //      8192 B
  unsigned short* hbuf = (unsigned short*)(ws + 137371648);     //    131072 B
  int*            flags= (int*)           (ws + 137502720);     //      1024 B
  unsigned short* xb16 = (unsigned short*)(ws + 137503744);     //  16777216 B

  const int pre = (ws_size >= (size_t)137503744 + 16777216) ? 1 : 0;

  prep_kernel<<<768, 256, 0, stream>>>(Wf, bWf, Wi, bWi, Wo, bWo, Wc, bWc,
                                       Uf, bUf, Ui, bUi, Uo, bUo, Uc, bUc,
                                       Wall, Uall, ball, flags, x, xb16, pre);
  if (pre)
    xw_gemm_pre<<<dim3(16, 256), 256, 0, stream>>>(xb16, Wall, ball, xw);
  else
    xw_gemm<<<dim3(16, 256), 256, 0, stream>>>(x, Wall, ball, xw);
  lstm_scan<<<64, 256, 0, stream>>>(xw, Uall, hbuf, flags, (float*)d_out);
}